// Round 1
// baseline (2847.767 us; speedup 1.0000x reference)
//
#include <hip/hip_runtime.h>
#include <math.h>

#define B_ 4
#define DS_ 8192
#define DC_ 64
#define LS_ 256
#define LC_ 128
#define H_ 8
#define DH_ 16
#define INNER_ 128
#define FFH_ 16384
#define NLAT_ (B_*LS_)          // 1024
#define LATSZ_ (B_*LS_*LC_)     // 131072

// ---------------------------------------------------------------------------
// Generic tiled fp32 GEMM.  C = alpha*(A@B + bias) + beta*res, or atomicAdd.
// All row-major. M,N implied by grid; must divide BM/BN; K divides BK.
// ---------------------------------------------------------------------------
struct GemmP {
  const float* A; const float* Bm; float* C;
  const float* bias; const float* res;
  int lda, ldb, ldc;
  float alpha, beta;
  int K, ksplit;
};

template<int BM,int BN,int BK,int TM,int TN,bool ATOMIC>
__global__ __launch_bounds__(256) void gemm_k(GemmP p)
{
  __shared__ float As[BK][BM+4];
  __shared__ float Bs[BK][BN+4];
  const int bm = blockIdx.y * BM;
  const int bn = blockIdx.x * BN;
  const int tid = threadIdx.x;
  constexpr int NTX = BN / TN;
  const int tx = tid % NTX;
  const int ty = tid / NTX;
  const int k0 = ATOMIC ? blockIdx.z * p.ksplit : 0;
  const int k1 = ATOMIC ? k0 + p.ksplit : p.K;
  float acc[TM][TN];
#pragma unroll
  for (int i=0;i<TM;i++)
#pragma unroll
    for (int j=0;j<TN;j++) acc[i][j]=0.f;

  for (int kb=k0; kb<k1; kb+=BK) {
#pragma unroll
    for (int e=tid; e<BM*BK; e+=256) {
      int r=e/BK, c=e%BK;
      As[c][r] = p.A[(size_t)(bm+r)*p.lda + kb + c];
    }
#pragma unroll
    for (int e=tid; e<BK*BN; e+=256) {
      int r=e/BN, c=e%BN;
      Bs[r][c] = p.Bm[(size_t)(kb+r)*p.ldb + bn + c];
    }
    __syncthreads();
#pragma unroll
    for (int kk=0;kk<BK;kk++) {
      float a[TM], b[TN];
#pragma unroll
      for (int i=0;i<TM;i++) a[i]=As[kk][ty*TM+i];
#pragma unroll
      for (int j=0;j<TN;j++) b[j]=Bs[kk][tx*TN+j];
#pragma unroll
      for (int i=0;i<TM;i++)
#pragma unroll
        for (int j=0;j<TN;j++) acc[i][j]=fmaf(a[i],b[j],acc[i][j]);
    }
    __syncthreads();
  }

#pragma unroll
  for (int i=0;i<TM;i++) {
    const size_t row = bm + ty*TM + i;
#pragma unroll
    for (int j=0;j<TN;j++) {
      const int col = bn + tx*TN + j;
      if (ATOMIC) {
        atomicAdd(&p.C[row*p.ldc + col], acc[i][j]);
      } else {
        float v = acc[i][j];
        if (p.bias) v += p.bias[col];
        v *= p.alpha;
        if (p.beta != 0.f) v += p.beta * p.res[row*p.ldc + col];
        p.C[row*p.ldc + col] = v;
      }
    }
  }
}

// Fused Q/K/V projection: same GEMM, blockIdx.z picks weight/output. No bias.
template<int BM,int BN,int BK,int TM,int TN>
__global__ __launch_bounds__(256) void gemm_qkv_k(
    const float* __restrict__ A, int lda,
    const float* __restrict__ B0, const float* __restrict__ B1, const float* __restrict__ B2,
    int ldb, float* C0, float* C1, float* C2, int ldc, int K)
{
  const float* Bm = (blockIdx.z==0)?B0:((blockIdx.z==1)?B1:B2);
  float*       C  = (blockIdx.z==0)?C0:((blockIdx.z==1)?C1:C2);
  __shared__ float As[BK][BM+4];
  __shared__ float Bs[BK][BN+4];
  const int bm = blockIdx.y * BM;
  const int bn = blockIdx.x * BN;
  const int tid = threadIdx.x;
  constexpr int NTX = BN / TN;
  const int tx = tid % NTX;
  const int ty = tid / NTX;
  float acc[TM][TN];
#pragma unroll
  for (int i=0;i<TM;i++)
#pragma unroll
    for (int j=0;j<TN;j++) acc[i][j]=0.f;
  for (int kb=0; kb<K; kb+=BK) {
#pragma unroll
    for (int e=tid; e<BM*BK; e+=256) {
      int r=e/BK, c=e%BK;
      As[c][r] = A[(size_t)(bm+r)*lda + kb + c];
    }
#pragma unroll
    for (int e=tid; e<BK*BN; e+=256) {
      int r=e/BN, c=e%BN;
      Bs[r][c] = Bm[(size_t)(kb+r)*ldb + bn + c];
    }
    __syncthreads();
#pragma unroll
    for (int kk=0;kk<BK;kk++) {
      float a[TM], b[TN];
#pragma unroll
      for (int i=0;i<TM;i++) a[i]=As[kk][ty*TM+i];
#pragma unroll
      for (int j=0;j<TN;j++) b[j]=Bs[kk][tx*TN+j];
#pragma unroll
      for (int i=0;i<TM;i++)
#pragma unroll
        for (int j=0;j<TN;j++) acc[i][j]=fmaf(a[i],b[j],acc[i][j]);
    }
    __syncthreads();
  }
#pragma unroll
  for (int i=0;i<TM;i++) {
    const size_t row = bm + ty*TM + i;
#pragma unroll
    for (int j=0;j<TN;j++) {
      const int col = bn + tx*TN + j;
      C[row*ldc + col] = acc[i][j];
    }
  }
}

// ---------------------------------------------------------------------------
// FFW hidden: h = (xn@W1[:,c0+j]+b1[c0+j]) * gelu(xn@W1[:,FFH+c0+j]+b1[FFH+c0+j])
// Dual-accumulator GEMM, exact erf GELU.  A = xn (1024x128), K=128 fixed.
// ---------------------------------------------------------------------------
template<int BM,int BN,int BK,int TM,int TN>
__global__ __launch_bounds__(256) void ffw_hidden_k(
    const float* __restrict__ A,   // xn: NLAT_ x LC_
    const float* __restrict__ W1,  // LC_ x 2*FFH_
    const float* __restrict__ b1,  // 2*FFH_
    float* __restrict__ Hb,        // NLAT_ x CH
    int c0, int CH)
{
  __shared__ float As [BK][BM+4];
  __shared__ float B1s[BK][BN+4];
  __shared__ float B2s[BK][BN+4];
  const int bm = blockIdx.y * BM;
  const int bn = blockIdx.x * BN;
  const int tid = threadIdx.x;
  constexpr int NTX = BN / TN;
  const int tx = tid % NTX;
  const int ty = tid / NTX;
  float acc1[TM][TN], acc2[TM][TN];
#pragma unroll
  for (int i=0;i<TM;i++)
#pragma unroll
    for (int j=0;j<TN;j++) { acc1[i][j]=0.f; acc2[i][j]=0.f; }

  for (int kb=0; kb<LC_; kb+=BK) {
#pragma unroll
    for (int e=tid; e<BM*BK; e+=256) {
      int r=e/BK, c=e%BK;
      As[c][r] = A[(size_t)(bm+r)*LC_ + kb + c];
    }
#pragma unroll
    for (int e=tid; e<BK*BN; e+=256) {
      int r=e/BN, c=e%BN;
      size_t base = (size_t)(kb+r)*(2*FFH_) + c0 + bn + c;
      B1s[r][c] = W1[base];
      B2s[r][c] = W1[base + FFH_];
    }
    __syncthreads();
#pragma unroll
    for (int kk=0;kk<BK;kk++) {
      float a[TM], u[TN], v[TN];
#pragma unroll
      for (int i=0;i<TM;i++) a[i]=As[kk][ty*TM+i];
#pragma unroll
      for (int j=0;j<TN;j++) { u[j]=B1s[kk][tx*TN+j]; v[j]=B2s[kk][tx*TN+j]; }
#pragma unroll
      for (int i=0;i<TM;i++)
#pragma unroll
        for (int j=0;j<TN;j++) {
          acc1[i][j]=fmaf(a[i],u[j],acc1[i][j]);
          acc2[i][j]=fmaf(a[i],v[j],acc2[i][j]);
        }
    }
    __syncthreads();
  }

#pragma unroll
  for (int i=0;i<TM;i++) {
    const size_t row = bm + ty*TM + i;
#pragma unroll
    for (int j=0;j<TN;j++) {
      const int colc = bn + tx*TN + j;      // col within chunk
      const int colg = c0 + colc;           // global col in [0,FFH)
      float u1 = acc1[i][j] + b1[colg];
      float u2 = acc2[i][j] + b1[FFH_ + colg];
      float ge = 0.5f * u2 * (1.0f + erff(u2 * 0.70710678118654752f));
      Hb[row*CH + colc] = u1 * ge;
    }
  }
}

// ---------------------------------------------------------------------------
// Flash-style attention partials. Layouts are GEMM-native [b, tok, h*16+d].
// One block per (b,h,split); 256 threads = 256 latent rows; K/V chunks in LDS.
// part[(bh*nsplit+split)*256 + l] = {m, sum, acc[16]}  (stride 18 floats)
// ---------------------------------------------------------------------------
__global__ __launch_bounds__(256) void attn_partial_k(
    const float* __restrict__ Q, const float* __restrict__ K,
    const float* __restrict__ V, float* __restrict__ part,
    int S, int nsplit)
{
  const int blk = blockIdx.x;
  const int split = blk % nsplit;
  const int bh = blk / nsplit;
  const int b = bh >> 3, h = bh & 7;
  const int l = threadIdx.x;

  const float* qp = Q + ((size_t)(b*LS_ + l)*INNER_ + h*DH_);
  float q[16];
  *(float4*)&q[0]  = *(const float4*)(qp);
  *(float4*)&q[4]  = *(const float4*)(qp+4);
  *(float4*)&q[8]  = *(const float4*)(qp+8);
  *(float4*)&q[12] = *(const float4*)(qp+12);

  const int len = S / nsplit;
  const int s0 = split * len;

  __shared__ float Ks[64][16];
  __shared__ float Vs[64][16];

  float m = -1e30f, sum = 0.f;
  float acc[16];
#pragma unroll
  for (int d=0; d<16; d++) acc[d]=0.f;

  const int r  = threadIdx.x >> 2;
  const int c4 = (threadIdx.x & 3) * 4;

  for (int sc = s0; sc < s0 + len; sc += 64) {
    __syncthreads();
    const size_t base = ((size_t)(b*S + sc + r))*INNER_ + h*DH_ + c4;
    *(float4*)&Ks[r][c4] = *(const float4*)(K + base);
    *(float4*)&Vs[r][c4] = *(const float4*)(V + base);
    __syncthreads();
#pragma unroll 4
    for (int j=0; j<64; j++) {
      const float* kj = &Ks[j][0];
      float dot = 0.f;
#pragma unroll
      for (int d=0; d<16; d++) dot = fmaf(q[d], kj[d], dot);
      float logit = dot * 0.25f;   // D^-0.5 = 16^-0.5
      const float* vj = &Vs[j][0];
      if (logit <= m) {
        float p = __expf(logit - m);
        sum += p;
#pragma unroll
        for (int d=0; d<16; d++) acc[d] = fmaf(p, vj[d], acc[d]);
      } else {
        float corr = __expf(m - logit);
        sum = fmaf(sum, corr, 1.0f);
#pragma unroll
        for (int d=0; d<16; d++) acc[d] = fmaf(acc[d], corr, vj[d]);
        m = logit;
      }
    }
  }
  float* pp = part + ((size_t)(bh*nsplit + split)*LS_ + l)*18;
  pp[0] = m; pp[1] = sum;
#pragma unroll
  for (int d=0; d<16; d++) pp[2+d] = acc[d];
}

__global__ __launch_bounds__(256) void attn_combine_k(
    const float* __restrict__ part, float* __restrict__ O, int nsplit)
{
  const int idx = blockIdx.x*256 + threadIdx.x;   // B_*H_*LS_ = 8192 total
  const int bh = idx >> 8;
  const int l  = idx & 255;
  const int b = bh >> 3, h = bh & 7;
  float M = -1e30f;
  for (int sp=0; sp<nsplit; sp++)
    M = fmaxf(M, part[((size_t)(bh*nsplit+sp)*LS_ + l)*18]);
  float sum = 0.f;
  float acc[16];
#pragma unroll
  for (int d=0; d<16; d++) acc[d]=0.f;
  for (int sp=0; sp<nsplit; sp++) {
    const float* pp = part + ((size_t)(bh*nsplit+sp)*LS_ + l)*18;
    float cf = __expf(pp[0] - M);
    sum = fmaf(pp[1], cf, sum);
#pragma unroll
    for (int d=0; d<16; d++) acc[d] = fmaf(pp[2+d], cf, acc[d]);
  }
  float inv = 1.0f / sum;
  float* op = O + ((size_t)(b*LS_ + l)*INNER_ + h*DH_);
#pragma unroll
  for (int d=0; d<16; d++) op[d] = acc[d]*inv;
}

// ---------------------------------------------------------------------------
// Small elementwise / norm kernels
// ---------------------------------------------------------------------------
__global__ __launch_bounds__(256) void bcast_k(const float* __restrict__ src,
                                               float* __restrict__ dst)
{
  int i = blockIdx.x*256 + threadIdx.x;           // LATSZ_
  dst[i] = src[i & (LS_*LC_ - 1)];
}

__global__ __launch_bounds__(256) void biasadd_k(float* __restrict__ x,
                                                 const float* __restrict__ b)
{
  int i = blockIdx.x*256 + threadIdx.x;           // LATSZ_
  x[i] += b[i & (LC_-1)];
}

__global__ __launch_bounds__(256) void ln_k(const float* __restrict__ x,
                                            const float* __restrict__ g,
                                            const float* __restrict__ bta,
                                            float* __restrict__ y, int rows)
{
  int w = (blockIdx.x * blockDim.x + threadIdx.x) >> 6;   // wave per row
  int lane = threadIdx.x & 63;
  if (w >= rows) return;
  const float* xr = x + (size_t)w*LC_;
  float x0 = xr[lane], x1 = xr[lane+64];
  float s = x0 + x1;
#pragma unroll
  for (int off=32; off; off>>=1) s += __shfl_xor(s, off);
  float mu = s * (1.0f/128.0f);
  float d0 = x0-mu, d1 = x1-mu;
  float v = d0*d0 + d1*d1;
#pragma unroll
  for (int off=32; off; off>>=1) v += __shfl_xor(v, off);
  float rstd = rsqrtf(v*(1.0f/128.0f) + 1e-5f);
  float* yr = y + (size_t)w*LC_;
  yr[lane]    = d0*rstd*g[lane]    + bta[lane];
  yr[lane+64] = d1*rstd*g[lane+64] + bta[lane+64];
}

// ---------------------------------------------------------------------------
// Host-side wrappers
// ---------------------------------------------------------------------------
static inline void gemm64(hipStream_t s, const float* A,int lda,const float* Bm,int ldb,
    float* C,int ldc,const float* bias,const float* res,float alpha,float beta,
    int M,int N,int K)
{
  GemmP p; p.A=A;p.Bm=Bm;p.C=C;p.bias=bias;p.res=res;p.lda=lda;p.ldb=ldb;p.ldc=ldc;
  p.alpha=alpha;p.beta=beta;p.K=K;p.ksplit=0;
  hipLaunchKernelGGL((gemm_k<64,64,16,4,4,false>), dim3(N/64,M/64,1), dim3(256), 0, s, p);
}
static inline void gemm32(hipStream_t s, const float* A,int lda,const float* Bm,int ldb,
    float* C,int ldc,const float* bias,const float* res,float alpha,float beta,
    int M,int N,int K)
{
  GemmP p; p.A=A;p.Bm=Bm;p.C=C;p.bias=bias;p.res=res;p.lda=lda;p.ldb=ldb;p.ldc=ldc;
  p.alpha=alpha;p.beta=beta;p.K=K;p.ksplit=0;
  hipLaunchKernelGGL((gemm_k<32,32,16,2,2,false>), dim3(N/32,M/32,1), dim3(256), 0, s, p);
}

extern "C" void kernel_launch(void* const* d_in, const int* in_sizes, int n_in,
                              void* d_out, int out_size, void* d_ws, size_t ws_size,
                              hipStream_t stream)
{
  (void)in_sizes; (void)n_in; (void)out_size;
  const float* data    = (const float*)d_in[0];
  const float* inilat  = (const float*)d_in[1];
  const float* ca_Wq   = (const float*)d_in[2];
  const float* ca_Wk   = (const float*)d_in[3];
  const float* ca_Wv   = (const float*)d_in[4];
  const float* ca_Wo   = (const float*)d_in[5];
  const float* ca_bo   = (const float*)d_in[6];
  const float* tr_Wq   = (const float*)d_in[7];
  const float* tr_Wk   = (const float*)d_in[8];
  const float* tr_Wv   = (const float*)d_in[9];
  const float* tr_Wo   = (const float*)d_in[10];
  const float* tr_bo   = (const float*)d_in[11];
  const float* caff_g  = (const float*)d_in[12];
  const float* caff_b  = (const float*)d_in[13];
  const float* caff_W1 = (const float*)d_in[14];
  const float* caff_b1 = (const float*)d_in[15];
  const float* caff_W2 = (const float*)d_in[16];
  const float* caff_b2 = (const float*)d_in[17];
  const float* trff_g  = (const float*)d_in[18];
  const float* trff_b  = (const float*)d_in[19];
  const float* trff_W1 = (const float*)d_in[20];
  const float* trff_b1 = (const float*)d_in[21];
  const float* trff_W2 = (const float*)d_in[22];
  const float* trff_b2 = (const float*)d_in[23];

  float* ws  = (float*)d_ws;
  float* lat = ws;
  float* Qb  = lat + LATSZ_;
  float* Kl  = Qb + LATSZ_;
  float* Vl  = Kl + LATSZ_;
  float* Ob  = Vl + LATSZ_;
  float* xn  = Ob + LATSZ_;
  float* zb  = xn + LATSZ_;
  float* Kd  = zb + LATSZ_;
  float* Vd  = Kd + (size_t)B_*DS_*INNER_;
  float* part= Vd + (size_t)B_*DS_*INNER_;
  float* hb  = part + (size_t)B_*H_*16*LS_*18;   // nsplit max 16

  long long avail = (long long)(ws_size/4) - (long long)(hb - ws);
  int CH = 4096;
  while (CH > 512 && (long long)NLAT_*CH > avail) CH >>= 1;

  // 0. broadcast init latents
  hipLaunchKernelGGL(bcast_k, dim3(LATSZ_/256), dim3(256), 0, stream, inilat, lat);
  // 1. shared data K/V projections (weights reused by all 3 cross-attends)
  gemm64(stream, data, DC_, ca_Wk, INNER_, Kd, INNER_, nullptr, nullptr, 1.f, 0.f, B_*DS_, INNER_, DC_);
  gemm64(stream, data, DC_, ca_Wv, INNER_, Vd, INNER_, nullptr, nullptr, 1.f, 0.f, B_*DS_, INNER_, DC_);

  auto cross_attend = [&](float alpha, float beta) {
    gemm32(stream, lat, LC_, ca_Wq, INNER_, Qb, INNER_, nullptr, nullptr, 1.f, 0.f, NLAT_, INNER_, LC_);
    hipLaunchKernelGGL(attn_partial_k, dim3(B_*H_*16), dim3(256), 0, stream, Qb, Kd, Vd, part, DS_, 16);
    hipLaunchKernelGGL(attn_combine_k, dim3(B_*H_*LS_/256), dim3(256), 0, stream, part, Ob, 16);
    gemm32(stream, Ob, INNER_, ca_Wo, LC_, lat, LC_, ca_bo, lat, alpha, beta, NLAT_, LC_, INNER_);
  };

  auto self_layer = [&](const float* in, float* out, int t, float alpha, float beta, const float* res) {
    hipLaunchKernelGGL((gemm_qkv_k<32,32,16,2,2>), dim3(INNER_/32, NLAT_/32, 3), dim3(256), 0, stream,
        in, LC_,
        tr_Wq + (size_t)t*LC_*INNER_, tr_Wk + (size_t)t*LC_*INNER_, tr_Wv + (size_t)t*LC_*INNER_,
        INNER_, Qb, Kl, Vl, INNER_, LC_);
    hipLaunchKernelGGL(attn_partial_k, dim3(B_*H_*1), dim3(256), 0, stream, Qb, Kl, Vl, part, LS_, 1);
    hipLaunchKernelGGL(attn_combine_k, dim3(B_*H_*LS_/256), dim3(256), 0, stream, part, Ob, 1);
    gemm32(stream, Ob, INNER_, tr_Wo + (size_t)t*INNER_*LC_, LC_, out, LC_,
           tr_bo + (size_t)t*LC_, res, alpha, beta, NLAT_, LC_, INNER_);
  };

  auto ffw = [&](const float* g, const float* bta, const float* W1, const float* b1,
                 const float* W2, const float* b2) {
    hipLaunchKernelGGL(ln_k, dim3(NLAT_/4), dim3(256), 0, stream, lat, g, bta, xn, NLAT_);
    hipLaunchKernelGGL(biasadd_k, dim3(LATSZ_/256), dim3(256), 0, stream, lat, b2);
    for (int c0 = 0; c0 < FFH_; c0 += CH) {
      hipLaunchKernelGGL((ffw_hidden_k<64,64,16,4,4>), dim3(CH/64, NLAT_/64), dim3(256), 0, stream,
                         xn, W1, b1, hb, c0, CH);
      GemmP p; p.A=hb; p.Bm=W2 + (size_t)c0*LC_; p.C=lat; p.bias=nullptr; p.res=nullptr;
      p.lda=CH; p.ldb=LC_; p.ldc=LC_; p.alpha=1.f; p.beta=0.f; p.K=CH; p.ksplit=512;
      hipLaunchKernelGGL((gemm_k<64,64,16,4,4,true>), dim3(LC_/64, NLAT_/64, CH/512), dim3(256), 0, stream, p);
    }
  };

  // initial cross attention (no residual)
  cross_attend(1.f, 0.f);
  // initial transformer (no residual)
  self_layer(lat, zb, 0, 1.f, 0.f, nullptr);
  self_layer(zb, lat, 1, 1.f, 0.f, nullptr);

  for (int na = 0; na < 2; na++) {
    cross_attend(0.5f, 0.5f);                       // (attn + lat)/2
    ffw(caff_g, caff_b, caff_W1, caff_b1, caff_W2, caff_b2);
    self_layer(lat, zb, 0, 1.f, 0.f, nullptr);      // z = attn(lat)
    self_layer(zb, lat, 1, 0.5f, 0.5f, lat);        // lat = (attn(z)+lat)/2
    ffw(trff_g, trff_b, trff_W1, trff_b1, trff_W2, trff_b2);
  }

  hipMemcpyAsync(d_out, lat, (size_t)LATSZ_*sizeof(float), hipMemcpyDeviceToDevice, stream);
}

// Round 2
// 1224.874 us; speedup vs baseline: 2.3249x; 2.3249x over previous
//
#include <hip/hip_runtime.h>
#include <math.h>

#define B_ 4
#define DS_ 8192
#define DC_ 64
#define LS_ 256
#define LC_ 128
#define H_ 8
#define DH_ 16
#define INNER_ 128
#define FFH_ 16384
#define NLAT_ (B_*LS_)          // 1024
#define LATSZ_ (B_*LS_*LC_)     // 131072
#define NSPL_CROSS 32
#define NSPL_SELF 4
#define CH_ 4096                // FFW column chunk

typedef __attribute__((ext_vector_type(8))) short s16x8;
typedef __attribute__((ext_vector_type(4))) float f32x4;

static __device__ __forceinline__ f32x4 MFMA(s16x8 a, s16x8 b, f32x4 c){
  return __builtin_amdgcn_mfma_f32_16x16x32_bf16(a, b, c, 0, 0, 0);
}
static __device__ __forceinline__ unsigned short f2bf(float f){
  unsigned u = __float_as_uint(f);
  return (unsigned short)((u + 0x7fffu + ((u>>16)&1u)) >> 16);
}

// ---------------------------------------------------------------------------
// fp32 tiled GEMM (kept for projections).  C = alpha*(A@B + bias) + beta*res
// ---------------------------------------------------------------------------
struct GemmP {
  const float* A; const float* Bm; float* C;
  const float* bias; const float* res;
  int lda, ldb, ldc;
  float alpha, beta;
  int K;
};

template<int BM,int BN,int BK,int TM,int TN>
__global__ __launch_bounds__(256) void gemm_k(GemmP p)
{
  __shared__ float As[BK][BM+4];
  __shared__ float Bs[BK][BN+4];
  const int bm = blockIdx.y * BM;
  const int bn = blockIdx.x * BN;
  const int tid = threadIdx.x;
  constexpr int NTX = BN / TN;
  const int tx = tid % NTX;
  const int ty = tid / NTX;
  float acc[TM][TN];
#pragma unroll
  for (int i=0;i<TM;i++)
#pragma unroll
    for (int j=0;j<TN;j++) acc[i][j]=0.f;

  for (int kb=0; kb<p.K; kb+=BK) {
#pragma unroll
    for (int e=tid; e<BM*BK; e+=256) {
      int r=e/BK, c=e%BK;
      As[c][r] = p.A[(size_t)(bm+r)*p.lda + kb + c];
    }
#pragma unroll
    for (int e=tid; e<BK*BN; e+=256) {
      int r=e/BN, c=e%BN;
      Bs[r][c] = p.Bm[(size_t)(kb+r)*p.ldb + bn + c];
    }
    __syncthreads();
#pragma unroll
    for (int kk=0;kk<BK;kk++) {
      float a[TM], b[TN];
#pragma unroll
      for (int i=0;i<TM;i++) a[i]=As[kk][ty*TM+i];
#pragma unroll
      for (int j=0;j<TN;j++) b[j]=Bs[kk][tx*TN+j];
#pragma unroll
      for (int i=0;i<TM;i++)
#pragma unroll
        for (int j=0;j<TN;j++) acc[i][j]=fmaf(a[i],b[j],acc[i][j]);
    }
    __syncthreads();
  }
#pragma unroll
  for (int i=0;i<TM;i++) {
    const size_t row = bm + ty*TM + i;
#pragma unroll
    for (int j=0;j<TN;j++) {
      const int col = bn + tx*TN + j;
      float v = acc[i][j];
      if (p.bias) v += p.bias[col];
      v *= p.alpha;
      if (p.beta != 0.f) v += p.beta * p.res[row*p.ldc + col];
      p.C[row*p.ldc + col] = v;
    }
  }
}

template<int BM,int BN,int BK,int TM,int TN>
__global__ __launch_bounds__(256) void gemm_qkv_k(
    const float* __restrict__ A, int lda,
    const float* __restrict__ B0, const float* __restrict__ B1, const float* __restrict__ B2,
    int ldb, float* C0, float* C1, float* C2, int ldc, int K)
{
  const float* Bm = (blockIdx.z==0)?B0:((blockIdx.z==1)?B1:B2);
  float*       C  = (blockIdx.z==0)?C0:((blockIdx.z==1)?C1:C2);
  __shared__ float As[BK][BM+4];
  __shared__ float Bs[BK][BN+4];
  const int bm = blockIdx.y * BM;
  const int bn = blockIdx.x * BN;
  const int tid = threadIdx.x;
  constexpr int NTX = BN / TN;
  const int tx = tid % NTX;
  const int ty = tid / NTX;
  float acc[TM][TN];
#pragma unroll
  for (int i=0;i<TM;i++)
#pragma unroll
    for (int j=0;j<TN;j++) acc[i][j]=0.f;
  for (int kb=0; kb<K; kb+=BK) {
#pragma unroll
    for (int e=tid; e<BM*BK; e+=256) {
      int r=e/BK, c=e%BK;
      As[c][r] = A[(size_t)(bm+r)*lda + kb + c];
    }
#pragma unroll
    for (int e=tid; e<BK*BN; e+=256) {
      int r=e/BN, c=e%BN;
      Bs[r][c] = Bm[(size_t)(kb+r)*ldb + bn + c];
    }
    __syncthreads();
#pragma unroll
    for (int kk=0;kk<BK;kk++) {
      float a[TM], b[TN];
#pragma unroll
      for (int i=0;i<TM;i++) a[i]=As[kk][ty*TM+i];
#pragma unroll
      for (int j=0;j<TN;j++) b[j]=Bs[kk][tx*TN+j];
#pragma unroll
      for (int i=0;i<TM;i++)
#pragma unroll
        for (int j=0;j<TN;j++) acc[i][j]=fmaf(a[i],b[j],acc[i][j]);
    }
    __syncthreads();
  }
#pragma unroll
  for (int i=0;i<TM;i++) {
    const size_t row = bm + ty*TM + i;
#pragma unroll
    for (int j=0;j<TN;j++) {
      const int col = bn + tx*TN + j;
      C[row*ldc + col] = acc[i][j];
    }
  }
}

// ---------------------------------------------------------------------------
// Convert+transpose fp32 W[K][N] -> bf16 WT[N][K]
// ---------------------------------------------------------------------------
__global__ __launch_bounds__(256) void cvtT_k(const float* __restrict__ W,
                                              unsigned short* __restrict__ WT,
                                              int K, int N)
{
  __shared__ unsigned short t[32][33];
  const int kb = blockIdx.y*32, nb = blockIdx.x*32;
  const int tx = threadIdx.x & 31, ty = threadIdx.x >> 5;
#pragma unroll
  for (int i = ty; i < 32; i += 8)
    t[i][tx] = f2bf(W[(size_t)(kb+i)*N + nb + tx]);
  __syncthreads();
#pragma unroll
  for (int i = ty; i < 32; i += 8)
    WT[(size_t)(nb+i)*K + kb + tx] = t[tx][i];
}

// ---------------------------------------------------------------------------
// MFMA FFW hidden:  h[:, c0:c0+CH] = (xnb@W1a + b1a) * gelu(xnb@W1b + b1b)
// A = xnb [1024][128] bf16 row-major; W1T [2*FFH][128] bf16 (B^T layout).
// Block 64(M) x 64(N), K=128 full.  4 waves, each 32x32 per GEMM.
// ---------------------------------------------------------------------------
__global__ __launch_bounds__(256) void ffw_hidden_mfma_k(
    const unsigned short* __restrict__ Ab, const unsigned short* __restrict__ W1T,
    const float* __restrict__ b1, unsigned short* __restrict__ Hb, int c0)
{
  __shared__ char smem[48*1024];
  unsigned short* As  = (unsigned short*)smem;           // [64][128] swizzled
  unsigned short* B1s = (unsigned short*)(smem+16384);
  unsigned short* B2s = (unsigned short*)(smem+32768);
  const int bm = blockIdx.y*64, bn = blockIdx.x*64;
  const int tid = threadIdx.x;
#pragma unroll
  for (int p=0;p<4;p++){
    int e = tid + p*256; int row = e>>4, cb = e&15;
    int sw = (cb ^ (row&7))*16;
    *(s16x8*)((char*)As  + row*256 + sw) = *(const s16x8*)(Ab  + (size_t)(bm+row)*LC_ + cb*8);
    *(s16x8*)((char*)B1s + row*256 + sw) = *(const s16x8*)(W1T + (size_t)(c0+bn+row)*LC_ + cb*8);
    *(s16x8*)((char*)B2s + row*256 + sw) = *(const s16x8*)(W1T + ((size_t)FFH_+c0+bn+row)*LC_ + cb*8);
  }
  __syncthreads();
  const int lane = tid&63, wid = tid>>6;
  const int wr = (wid>>1)*32, wc = (wid&1)*32;
  const int r = lane&15, g = lane>>4;
  f32x4 acc1[2][2], acc2[2][2];
#pragma unroll
  for (int mi=0;mi<2;mi++)
#pragma unroll
    for (int ni=0;ni<2;ni++){ acc1[mi][ni]=(f32x4){0,0,0,0}; acc2[mi][ni]=(f32x4){0,0,0,0}; }
#pragma unroll
  for (int ks=0; ks<4; ks++){
    const int cb = ks*4 + g;
    s16x8 a[2], bf1[2], bf2[2];
#pragma unroll
    for (int mi=0;mi<2;mi++){
      int row = wr+mi*16+r; int sw=(cb^(row&7))*16;
      a[mi] = *(const s16x8*)((const char*)As + row*256 + sw);
    }
#pragma unroll
    for (int ni=0;ni<2;ni++){
      int row = wc+ni*16+r; int sw=(cb^(row&7))*16;
      bf1[ni] = *(const s16x8*)((const char*)B1s + row*256 + sw);
      bf2[ni] = *(const s16x8*)((const char*)B2s + row*256 + sw);
    }
#pragma unroll
    for (int mi=0;mi<2;mi++)
#pragma unroll
      for (int ni=0;ni<2;ni++){
        acc1[mi][ni] = MFMA(a[mi], bf1[ni], acc1[mi][ni]);
        acc2[mi][ni] = MFMA(a[mi], bf2[ni], acc2[mi][ni]);
      }
  }
  __syncthreads();                     // done reading tiles; reuse smem
  unsigned short* Ts = (unsigned short*)smem;   // [64][72]
#pragma unroll
  for (int mi=0;mi<2;mi++)
#pragma unroll
    for (int ni=0;ni<2;ni++)
#pragma unroll
      for (int q=0;q<4;q++){
        int row = wr + mi*16 + g*4 + q;
        int col = wc + ni*16 + r;
        int colg = c0 + bn + col;
        float u1 = acc1[mi][ni][q] + b1[colg];
        float u2 = acc2[mi][ni][q] + b1[FFH_ + colg];
        float ge = 0.5f*u2*(1.0f + erff(u2*0.70710678118654752440f));
        Ts[row*72 + col] = f2bf(u1*ge);
      }
  __syncthreads();
#pragma unroll
  for (int p=0;p<2;p++){
    int e = tid + p*256; int row = e>>3, cb = e&7;
    *(s16x8*)(Hb + (size_t)(bm+row)*CH_ + bn + cb*8) =
        *(const s16x8*)((const char*)Ts + row*144 + cb*16);
  }
}

// ---------------------------------------------------------------------------
// MFMA FFW second GEMM, split-K, atomic accumulate into fp32 lat.
// A = Hb [1024][CH] bf16; BT = W2T [128][16384] bf16.  Block 64x128, K=256.
// ---------------------------------------------------------------------------
__global__ __launch_bounds__(256) void ffw2_mfma_k(
    const unsigned short* __restrict__ Hb, const unsigned short* __restrict__ W2T,
    float* __restrict__ C, int c0)
{
  __shared__ char smem[24*1024];
  unsigned short* As = (unsigned short*)smem;          // [64][64] swizzled
  unsigned short* Bs = (unsigned short*)(smem+8192);   // [128][64] swizzled
  const int bm = blockIdx.y*64;
  const int k0 = blockIdx.x*256;
  const int tid = threadIdx.x;
  const int lane = tid&63, wid = tid>>6;
  const int wr = (wid>>1)*32, wc = (wid&1)*64;
  const int r = lane&15, g = lane>>4;
  f32x4 acc[2][4];
#pragma unroll
  for (int mi=0;mi<2;mi++)
#pragma unroll
    for (int ni=0;ni<4;ni++) acc[mi][ni]=(f32x4){0,0,0,0};

  for (int kb=0; kb<256; kb+=64){
    __syncthreads();
#pragma unroll
    for (int p=0;p<2;p++){
      int e = tid + p*256; int row=e>>3, cb=e&7;
      int sw = (cb ^ (row&7))*16;
      *(s16x8*)((char*)As + row*128 + sw) =
          *(const s16x8*)(Hb + (size_t)(bm+row)*CH_ + k0+kb+cb*8);
    }
#pragma unroll
    for (int p=0;p<4;p++){
      int e = tid + p*256; int row=e>>3, cb=e&7;
      int sw = (cb ^ (row&7))*16;
      *(s16x8*)((char*)Bs + row*128 + sw) =
          *(const s16x8*)(W2T + (size_t)row*FFH_ + c0+k0+kb+cb*8);
    }
    __syncthreads();
#pragma unroll
    for (int ks=0; ks<2; ks++){
      const int cb = ks*4 + g;
      s16x8 a[2], b[4];
#pragma unroll
      for (int mi=0;mi<2;mi++){
        int row = wr+mi*16+r; int sw=(cb^(row&7))*16;
        a[mi] = *(const s16x8*)((const char*)As + row*128 + sw);
      }
#pragma unroll
      for (int ni=0;ni<4;ni++){
        int row = wc+ni*16+r; int sw=(cb^(row&7))*16;
        b[ni] = *(const s16x8*)((const char*)Bs + row*128 + sw);
      }
#pragma unroll
      for (int mi=0;mi<2;mi++)
#pragma unroll
        for (int ni=0;ni<4;ni++)
          acc[mi][ni] = MFMA(a[mi], b[ni], acc[mi][ni]);
    }
  }
#pragma unroll
  for (int mi=0;mi<2;mi++)
#pragma unroll
    for (int ni=0;ni<4;ni++)
#pragma unroll
      for (int q=0;q<4;q++){
        int row = bm + wr + mi*16 + g*4 + q;
        int col = wc + ni*16 + r;
        atomicAdd(&C[(size_t)row*LC_ + col], acc[mi][ni][q]);
      }
}

// ---------------------------------------------------------------------------
// Attention partials (fp32, SoA part layout), combine, small kernels
// ---------------------------------------------------------------------------
__global__ __launch_bounds__(256) void attn_partial_k(
    const float* __restrict__ Q, const float* __restrict__ K,
    const float* __restrict__ V, float* __restrict__ part,
    int S, int nsplit)
{
  const int blk = blockIdx.x;
  const int split = blk % nsplit;
  const int bh = blk / nsplit;
  const int b = bh >> 3, h = bh & 7;
  const int l = threadIdx.x;

  const float* qp = Q + ((size_t)(b*LS_ + l)*INNER_ + h*DH_);
  float q[16];
  *(float4*)&q[0]  = *(const float4*)(qp);
  *(float4*)&q[4]  = *(const float4*)(qp+4);
  *(float4*)&q[8]  = *(const float4*)(qp+8);
  *(float4*)&q[12] = *(const float4*)(qp+12);

  const int len = S / nsplit;
  const int s0 = split * len;

  __shared__ float Ks[64][16];
  __shared__ float Vs[64][16];

  float m = -1e30f, sum = 0.f;
  float acc[16];
#pragma unroll
  for (int d=0; d<16; d++) acc[d]=0.f;

  const int r  = threadIdx.x >> 2;
  const int c4 = (threadIdx.x & 3) * 4;

  for (int sc = s0; sc < s0 + len; sc += 64) {
    __syncthreads();
    const size_t base = ((size_t)(b*S + sc + r))*INNER_ + h*DH_ + c4;
    *(float4*)&Ks[r][c4] = *(const float4*)(K + base);
    *(float4*)&Vs[r][c4] = *(const float4*)(V + base);
    __syncthreads();
#pragma unroll 4
    for (int j=0; j<64; j++) {
      const float* kj = &Ks[j][0];
      float dot = 0.f;
#pragma unroll
      for (int d=0; d<16; d++) dot = fmaf(q[d], kj[d], dot);
      float logit = dot * 0.25f;
      const float* vj = &Vs[j][0];
      if (logit <= m) {
        float p = __expf(logit - m);
        sum += p;
#pragma unroll
        for (int d=0; d<16; d++) acc[d] = fmaf(p, vj[d], acc[d]);
      } else {
        float corr = __expf(m - logit);
        sum = fmaf(sum, corr, 1.0f);
#pragma unroll
        for (int d=0; d<16; d++) acc[d] = fmaf(acc[d], corr, vj[d]);
        m = logit;
      }
    }
  }
  float* pp = part + (size_t)(bh*nsplit + split)*(LS_*18);
  pp[l] = m; pp[LS_ + l] = sum;
#pragma unroll
  for (int d=0; d<16; d++) pp[(2+d)*LS_ + l] = acc[d];
}

__global__ __launch_bounds__(256) void attn_combine_k(
    const float* __restrict__ part, float* __restrict__ O, int nsplit)
{
  const int idx = blockIdx.x*256 + threadIdx.x;
  const int bh = idx >> 8;
  const int l  = idx & 255;
  const int b = bh >> 3, h = bh & 7;
  float M = -1e30f;
  for (int sp=0; sp<nsplit; sp++)
    M = fmaxf(M, part[(size_t)(bh*nsplit+sp)*(LS_*18) + l]);
  float sum = 0.f;
  float acc[16];
#pragma unroll
  for (int d=0; d<16; d++) acc[d]=0.f;
  for (int sp=0; sp<nsplit; sp++) {
    const float* pp = part + (size_t)(bh*nsplit+sp)*(LS_*18);
    float cf = __expf(pp[l] - M);
    sum = fmaf(pp[LS_+l], cf, sum);
#pragma unroll
    for (int d=0; d<16; d++) acc[d] = fmaf(pp[(2+d)*LS_+l], cf, acc[d]);
  }
  float inv = 1.0f / sum;
  float* op = O + ((size_t)(b*LS_ + l)*INNER_ + h*DH_);
#pragma unroll
  for (int d=0; d<16; d++) op[d] = acc[d]*inv;
}

__global__ __launch_bounds__(256) void bcast_k(const float* __restrict__ src,
                                               float* __restrict__ dst)
{
  int i = blockIdx.x*256 + threadIdx.x;
  dst[i] = src[i & (LS_*LC_ - 1)];
}

__global__ __launch_bounds__(256) void biasadd_k(float* __restrict__ x,
                                                 const float* __restrict__ b)
{
  int i = blockIdx.x*256 + threadIdx.x;
  x[i] += b[i & (LC_-1)];
}

// LayerNorm -> bf16 output
__global__ __launch_bounds__(256) void ln_k(const float* __restrict__ x,
                                            const float* __restrict__ g,
                                            const float* __restrict__ bta,
                                            unsigned short* __restrict__ yb, int rows)
{
  int w = (blockIdx.x * blockDim.x + threadIdx.x) >> 6;
  int lane = threadIdx.x & 63;
  if (w >= rows) return;
  const float* xr = x + (size_t)w*LC_;
  float x0 = xr[lane], x1 = xr[lane+64];
  float s = x0 + x1;
#pragma unroll
  for (int off=32; off; off>>=1) s += __shfl_xor(s, off);
  float mu = s * (1.0f/128.0f);
  float d0 = x0-mu, d1 = x1-mu;
  float v = d0*d0 + d1*d1;
#pragma unroll
  for (int off=32; off; off>>=1) v += __shfl_xor(v, off);
  float rstd = rsqrtf(v*(1.0f/128.0f) + 1e-5f);
  unsigned short* yr = yb + (size_t)w*LC_;
  yr[lane]    = f2bf(d0*rstd*g[lane]    + bta[lane]);
  yr[lane+64] = f2bf(d1*rstd*g[lane+64] + bta[lane+64]);
}

// ---------------------------------------------------------------------------
static inline void gemm64(hipStream_t s, const float* A,int lda,const float* Bm,int ldb,
    float* C,int ldc,const float* bias,const float* res,float alpha,float beta,
    int M,int N,int K)
{
  GemmP p; p.A=A;p.Bm=Bm;p.C=C;p.bias=bias;p.res=res;p.lda=lda;p.ldb=ldb;p.ldc=ldc;
  p.alpha=alpha;p.beta=beta;p.K=K;
  hipLaunchKernelGGL((gemm_k<64,64,16,4,4>), dim3(N/64,M/64,1), dim3(256), 0, s, p);
}
static inline void gemm32(hipStream_t s, const float* A,int lda,const float* Bm,int ldb,
    float* C,int ldc,const float* bias,const float* res,float alpha,float beta,
    int M,int N,int K)
{
  GemmP p; p.A=A;p.Bm=Bm;p.C=C;p.bias=bias;p.res=res;p.lda=lda;p.ldb=ldb;p.ldc=ldc;
  p.alpha=alpha;p.beta=beta;p.K=K;
  hipLaunchKernelGGL((gemm_k<32,32,16,2,2>), dim3(N/32,M/32,1), dim3(256), 0, s, p);
}

extern "C" void kernel_launch(void* const* d_in, const int* in_sizes, int n_in,
                              void* d_out, int out_size, void* d_ws, size_t ws_size,
                              hipStream_t stream)
{
  (void)in_sizes; (void)n_in; (void)out_size; (void)ws_size;
  const float* data    = (const float*)d_in[0];
  const float* inilat  = (const float*)d_in[1];
  const float* ca_Wq   = (const float*)d_in[2];
  const float* ca_Wk   = (const float*)d_in[3];
  const float* ca_Wv   = (const float*)d_in[4];
  const float* ca_Wo   = (const float*)d_in[5];
  const float* ca_bo   = (const float*)d_in[6];
  const float* tr_Wq   = (const float*)d_in[7];
  const float* tr_Wk   = (const float*)d_in[8];
  const float* tr_Wv   = (const float*)d_in[9];
  const float* tr_Wo   = (const float*)d_in[10];
  const float* tr_bo   = (const float*)d_in[11];
  const float* caff_g  = (const float*)d_in[12];
  const float* caff_b  = (const float*)d_in[13];
  const float* caff_W1 = (const float*)d_in[14];
  const float* caff_b1 = (const float*)d_in[15];
  const float* caff_W2 = (const float*)d_in[16];
  const float* caff_b2 = (const float*)d_in[17];
  const float* trff_g  = (const float*)d_in[18];
  const float* trff_b  = (const float*)d_in[19];
  const float* trff_W1 = (const float*)d_in[20];
  const float* trff_b1 = (const float*)d_in[21];
  const float* trff_W2 = (const float*)d_in[22];
  const float* trff_b2 = (const float*)d_in[23];

  float* ws  = (float*)d_ws;
  float* lat = ws;
  float* Qb  = lat + LATSZ_;
  float* Kl  = Qb + LATSZ_;
  float* Vl  = Kl + LATSZ_;
  float* Ob  = Vl + LATSZ_;
  float* xn  = Ob + LATSZ_;          // unused fp32 slot (kept for alignment)
  float* zb  = xn + LATSZ_;
  float* Kd  = zb + LATSZ_;
  float* Vd  = Kd + (size_t)B_*DS_*INNER_;
  float* SH  = Vd + (size_t)B_*DS_*INNER_;           // part (attn) / h (ffw) alias
  float* part = SH;
  unsigned short* hb = (unsigned short*)SH;          // [1024][CH_] bf16
  float* after = SH + (size_t)B_*H_*NSPL_CROSS*LS_*18;
  unsigned short* xnb  = (unsigned short*)after;     // 1024*128
  unsigned short* W1Tc = xnb + (size_t)NLAT_*LC_;
  unsigned short* W1Tt = W1Tc + (size_t)2*FFH_*LC_;
  unsigned short* W2Tc = W1Tt + (size_t)2*FFH_*LC_;
  unsigned short* W2Tt = W2Tc + (size_t)FFH_*LC_;

  // --- weight conversions (bf16, transposed to B^T layout), every call ---
  hipLaunchKernelGGL(cvtT_k, dim3(2*FFH_/32, LC_/32), dim3(256), 0, stream, caff_W1, W1Tc, LC_, 2*FFH_);
  hipLaunchKernelGGL(cvtT_k, dim3(2*FFH_/32, LC_/32), dim3(256), 0, stream, trff_W1, W1Tt, LC_, 2*FFH_);
  hipLaunchKernelGGL(cvtT_k, dim3(LC_/32, FFH_/32), dim3(256), 0, stream, caff_W2, W2Tc, FFH_, LC_);
  hipLaunchKernelGGL(cvtT_k, dim3(LC_/32, FFH_/32), dim3(256), 0, stream, trff_W2, W2Tt, FFH_, LC_);

  hipLaunchKernelGGL(bcast_k, dim3(LATSZ_/256), dim3(256), 0, stream, inilat, lat);
  gemm64(stream, data, DC_, ca_Wk, INNER_, Kd, INNER_, nullptr, nullptr, 1.f, 0.f, B_*DS_, INNER_, DC_);
  gemm64(stream, data, DC_, ca_Wv, INNER_, Vd, INNER_, nullptr, nullptr, 1.f, 0.f, B_*DS_, INNER_, DC_);

  auto cross_attend = [&](float alpha, float beta) {
    gemm32(stream, lat, LC_, ca_Wq, INNER_, Qb, INNER_, nullptr, nullptr, 1.f, 0.f, NLAT_, INNER_, LC_);
    hipLaunchKernelGGL(attn_partial_k, dim3(B_*H_*NSPL_CROSS), dim3(256), 0, stream, Qb, Kd, Vd, part, DS_, NSPL_CROSS);
    hipLaunchKernelGGL(attn_combine_k, dim3(B_*H_*LS_/256), dim3(256), 0, stream, part, Ob, NSPL_CROSS);
    gemm32(stream, Ob, INNER_, ca_Wo, LC_, lat, LC_, ca_bo, lat, alpha, beta, NLAT_, LC_, INNER_);
  };

  auto self_layer = [&](const float* in, float* out, int t, float alpha, float beta, const float* res) {
    hipLaunchKernelGGL((gemm_qkv_k<32,32,16,2,2>), dim3(INNER_/32, NLAT_/32, 3), dim3(256), 0, stream,
        in, LC_,
        tr_Wq + (size_t)t*LC_*INNER_, tr_Wk + (size_t)t*LC_*INNER_, tr_Wv + (size_t)t*LC_*INNER_,
        INNER_, Qb, Kl, Vl, INNER_, LC_);
    hipLaunchKernelGGL(attn_partial_k, dim3(B_*H_*NSPL_SELF), dim3(256), 0, stream, Qb, Kl, Vl, part, LS_, NSPL_SELF);
    hipLaunchKernelGGL(attn_combine_k, dim3(B_*H_*LS_/256), dim3(256), 0, stream, part, Ob, NSPL_SELF);
    gemm32(stream, Ob, INNER_, tr_Wo + (size_t)t*INNER_*LC_, LC_, out, LC_,
           tr_bo + (size_t)t*LC_, res, alpha, beta, NLAT_, LC_, INNER_);
  };

  auto ffw = [&](const float* g, const float* bta,
                 const unsigned short* W1T, const float* b1,
                 const unsigned short* W2T, const float* b2) {
    hipLaunchKernelGGL(ln_k, dim3(NLAT_/4), dim3(256), 0, stream, lat, g, bta, xnb, NLAT_);
    hipLaunchKernelGGL(biasadd_k, dim3(LATSZ_/256), dim3(256), 0, stream, lat, b2);
    for (int c0 = 0; c0 < FFH_; c0 += CH_) {
      hipLaunchKernelGGL(ffw_hidden_mfma_k, dim3(CH_/64, NLAT_/64), dim3(256), 0, stream,
                         xnb, W1T, b1, hb, c0);
      hipLaunchKernelGGL(ffw2_mfma_k, dim3(CH_/256, NLAT_/64), dim3(256), 0, stream,
                         hb, W2T, lat, c0);
    }
  };

  cross_attend(1.f, 0.f);
  self_layer(lat, zb, 0, 1.f, 0.f, nullptr);
  self_layer(zb, lat, 1, 1.f, 0.f, nullptr);

  for (int na = 0; na < 2; na++) {
    cross_attend(0.5f, 0.5f);
    ffw(caff_g, caff_b, W1Tc, caff_b1, W2Tc, caff_b2);
    self_layer(lat, zb, 0, 1.f, 0.f, nullptr);
    self_layer(zb, lat, 1, 0.5f, 0.5f, lat);
    ffw(trff_g, trff_b, W1Tt, trff_b1, W2Tt, trff_b2);
  }

  hipMemcpyAsync(d_out, lat, (size_t)LATSZ_*sizeof(float), hipMemcpyDeviceToDevice, stream);
}

// Round 3
// 1034.286 us; speedup vs baseline: 2.7534x; 1.1843x over previous
//
#include <hip/hip_runtime.h>
#include <math.h>

#define B_ 4
#define DS_ 8192
#define DC_ 64
#define LS_ 256
#define LC_ 128
#define H_ 8
#define DH_ 16
#define INNER_ 128
#define FFH_ 16384
#define NLAT_ (B_*LS_)          // 1024
#define LATSZ_ (B_*LS_*LC_)     // 131072
#define NSPL_CROSS 16
#define NSPL_SELF 4
#define CH_ 8192                // FFW column chunk

typedef __attribute__((ext_vector_type(8))) short s16x8;
typedef __attribute__((ext_vector_type(4))) float f32x4;

static __device__ __forceinline__ f32x4 MFMA(s16x8 a, s16x8 b, f32x4 c){
  return __builtin_amdgcn_mfma_f32_16x16x32_bf16(a, b, c, 0, 0, 0);
}
static __device__ __forceinline__ unsigned short f2bf(float f){
  unsigned u = __float_as_uint(f);
  return (unsigned short)((u + 0x7fffu + ((u>>16)&1u)) >> 16);
}

// ---------------------------------------------------------------------------
// fp32 tiled GEMM (projections).  C = alpha*(A@B + bias) + beta*res
// OUTB: write bf16 (plain, alpha=1, no bias/res assumed by caller semantics ok)
// ---------------------------------------------------------------------------
struct GemmP {
  const float* A; const float* Bm; void* C;
  const float* bias; const float* res;
  int lda, ldb, ldc;
  float alpha, beta;
  int K;
};

template<int BM,int BN,int BK,int TM,int TN,bool OUTB>
__global__ __launch_bounds__(256) void gemm_k(GemmP p)
{
  __shared__ float As[BK][BM+4];
  __shared__ float Bs[BK][BN+4];
  const int bm = blockIdx.y * BM;
  const int bn = blockIdx.x * BN;
  const int tid = threadIdx.x;
  constexpr int NTX = BN / TN;
  const int tx = tid % NTX;
  const int ty = tid / NTX;
  float acc[TM][TN];
#pragma unroll
  for (int i=0;i<TM;i++)
#pragma unroll
    for (int j=0;j<TN;j++) acc[i][j]=0.f;

  for (int kb=0; kb<p.K; kb+=BK) {
#pragma unroll
    for (int e=tid; e<BM*BK; e+=256) {
      int r=e/BK, c=e%BK;
      As[c][r] = p.A[(size_t)(bm+r)*p.lda + kb + c];
    }
#pragma unroll
    for (int e=tid; e<BK*BN; e+=256) {
      int r=e/BN, c=e%BN;
      Bs[r][c] = p.Bm[(size_t)(kb+r)*p.ldb + bn + c];
    }
    __syncthreads();
#pragma unroll
    for (int kk=0;kk<BK;kk++) {
      float a[TM], b[TN];
#pragma unroll
      for (int i=0;i<TM;i++) a[i]=As[kk][ty*TM+i];
#pragma unroll
      for (int j=0;j<TN;j++) b[j]=Bs[kk][tx*TN+j];
#pragma unroll
      for (int i=0;i<TM;i++)
#pragma unroll
        for (int j=0;j<TN;j++) acc[i][j]=fmaf(a[i],b[j],acc[i][j]);
    }
    __syncthreads();
  }
#pragma unroll
  for (int i=0;i<TM;i++) {
    const size_t row = bm + ty*TM + i;
#pragma unroll
    for (int j=0;j<TN;j++) {
      const int col = bn + tx*TN + j;
      float v = acc[i][j];
      if (p.bias) v += p.bias[col];
      v *= p.alpha;
      if (p.beta != 0.f) v += p.beta * p.res[row*p.ldc + col];
      if (OUTB) ((unsigned short*)p.C)[row*p.ldc + col] = f2bf(v);
      else      ((float*)p.C)[row*p.ldc + col] = v;
    }
  }
}

// Fused Q/K/V self projection: bf16 outputs.
template<int BM,int BN,int BK,int TM,int TN>
__global__ __launch_bounds__(256) void gemm_qkv_k(
    const float* __restrict__ A, int lda,
    const float* __restrict__ B0, const float* __restrict__ B1, const float* __restrict__ B2,
    int ldb, unsigned short* C0, unsigned short* C1, unsigned short* C2, int ldc, int K)
{
  const float* Bm = (blockIdx.z==0)?B0:((blockIdx.z==1)?B1:B2);
  unsigned short* C  = (blockIdx.z==0)?C0:((blockIdx.z==1)?C1:C2);
  __shared__ float As[BK][BM+4];
  __shared__ float Bs[BK][BN+4];
  const int bm = blockIdx.y * BM;
  const int bn = blockIdx.x * BN;
  const int tid = threadIdx.x;
  constexpr int NTX = BN / TN;
  const int tx = tid % NTX;
  const int ty = tid / NTX;
  float acc[TM][TN];
#pragma unroll
  for (int i=0;i<TM;i++)
#pragma unroll
    for (int j=0;j<TN;j++) acc[i][j]=0.f;
  for (int kb=0; kb<K; kb+=BK) {
#pragma unroll
    for (int e=tid; e<BM*BK; e+=256) {
      int r=e/BK, c=e%BK;
      As[c][r] = A[(size_t)(bm+r)*lda + kb + c];
    }
#pragma unroll
    for (int e=tid; e<BK*BN; e+=256) {
      int r=e/BN, c=e%BN;
      Bs[r][c] = Bm[(size_t)(kb+r)*ldb + bn + c];
    }
    __syncthreads();
#pragma unroll
    for (int kk=0;kk<BK;kk++) {
      float a[TM], b[TN];
#pragma unroll
      for (int i=0;i<TM;i++) a[i]=As[kk][ty*TM+i];
#pragma unroll
      for (int j=0;j<TN;j++) b[j]=Bs[kk][tx*TN+j];
#pragma unroll
      for (int i=0;i<TM;i++)
#pragma unroll
        for (int j=0;j<TN;j++) acc[i][j]=fmaf(a[i],b[j],acc[i][j]);
    }
    __syncthreads();
  }
#pragma unroll
  for (int i=0;i<TM;i++) {
    const size_t row = bm + ty*TM + i;
#pragma unroll
    for (int j=0;j<TN;j++)
      C[row*ldc + bn + tx*TN + j] = f2bf(acc[i][j]);
  }
}

// ---------------------------------------------------------------------------
// Convert+transpose fp32 W[K][N] -> bf16 WT[N][K]
// ---------------------------------------------------------------------------
__global__ __launch_bounds__(256) void cvtT_k(const float* __restrict__ W,
                                              unsigned short* __restrict__ WT,
                                              int K, int N)
{
  __shared__ unsigned short t[32][33];
  const int kb = blockIdx.y*32, nb = blockIdx.x*32;
  const int tx = threadIdx.x & 31, ty = threadIdx.x >> 5;
#pragma unroll
  for (int i = ty; i < 32; i += 8)
    t[i][tx] = f2bf(W[(size_t)(kb+i)*N + nb + tx]);
  __syncthreads();
#pragma unroll
  for (int i = ty; i < 32; i += 8)
    WT[(size_t)(nb+i)*K + kb + tx] = t[tx][i];
}

// ---------------------------------------------------------------------------
// Flash MFMA attention partials.
// Q,K,V bf16 [B][S][INNER] (head h at cols h*16..+15). One block per
// (bh,split), 4 waves x 64 latent rows. Online softmax in exp2 domain.
// part[(bh*nsplit+split)]: SoA {m2[256], l[256], acc[16][256]}
// ---------------------------------------------------------------------------
__global__ __launch_bounds__(256) void flash_k(
    const unsigned short* __restrict__ Qb, const unsigned short* __restrict__ Kb,
    const unsigned short* __restrict__ Vb, float* __restrict__ part,
    int S, int nsplit)
{
  __shared__ __align__(16) char smem[44288];
  unsigned short* Ks = (unsigned short*)smem;                 // [64][40], stride 80B
  unsigned short* VT = (unsigned short*)(smem + 5120);        // [16][72], stride 144B
  const int tid = threadIdx.x, lane = tid & 63, wv = tid >> 6;
  unsigned short* Pw = (unsigned short*)(smem + 7424) + wv*64*72;  // [64][72]

  const int blk = blockIdx.x;
  const int split = blk % nsplit, bh = blk / nsplit;
  const int b = bh >> 3, h = bh & 7;
  const int r = lane & 15, g = lane >> 4;

  // zero K-dim pad (cols 16..31)
  {
    int t0 = tid >> 2, c0 = (tid & 3) * 4;
    *(ushort4*)&Ks[t0*40 + 16 + c0] = (ushort4){0,0,0,0};
  }

  // Q a-frags (K padded to 32; g>=2 lanes zero)
  s16x8 qa[4];
#pragma unroll
  for (int m=0;m<4;m++){
    if (g < 2)
      qa[m] = *(const s16x8*)(Qb + ((size_t)(b*LS_) + wv*64 + m*16 + r)*INNER_ + h*DH_ + g*8);
    else
      qa[m] = (s16x8){0,0,0,0,0,0,0,0};
  }

  float mrun[4][4], lrun[4][4];
  f32x4 oacc[4];
#pragma unroll
  for (int m=0;m<4;m++){
    oacc[m] = (f32x4){0,0,0,0};
#pragma unroll
    for (int q=0;q<4;q++){ mrun[m][q] = -1e30f; lrun[m][q] = 0.f; }
  }

  const int len = S / nsplit, s0 = split * len;
  const float C2 = 0.25f * 1.44269504f;   // scale * log2(e)

  for (int sc = s0; sc < s0 + len; sc += 64) {
    __syncthreads();
    {
      int t0 = tid >> 2, c0 = (tid & 3) * 4;
      size_t base = ((size_t)(b)*S + sc + t0)*INNER_ + h*DH_ + c0;
      ushort4 kv = *(const ushort4*)(Kb + base);
      *(ushort4*)&Ks[t0*40 + c0] = kv;
      ushort4 vv = *(const ushort4*)(Vb + base);
      VT[(c0+0)*72 + t0] = vv.x; VT[(c0+1)*72 + t0] = vv.y;
      VT[(c0+2)*72 + t0] = vv.z; VT[(c0+3)*72 + t0] = vv.w;
    }
    __syncthreads();

    // QK^T
    s16x8 bk[4];
#pragma unroll
    for (int n=0;n<4;n++) bk[n] = *(const s16x8*)&Ks[(n*16+r)*40 + g*8];
    f32x4 sv[4][4];
#pragma unroll
    for (int m=0;m<4;m++)
#pragma unroll
      for (int n=0;n<4;n++)
        sv[m][n] = MFMA(qa[m], bk[n], (f32x4){0,0,0,0});

    // online softmax (exp2 domain) + P -> bf16 LDS
#pragma unroll
    for (int m=0;m<4;m++){
#pragma unroll
      for (int q=0;q<4;q++){
        float x0=sv[m][0][q]*C2, x1=sv[m][1][q]*C2, x2=sv[m][2][q]*C2, x3=sv[m][3][q]*C2;
        float mx = fmaxf(fmaxf(x0,x1),fmaxf(x2,x3));
#pragma unroll
        for (int off=1; off<16; off<<=1) mx = fmaxf(mx, __shfl_xor(mx, off));
        float mo = mrun[m][q];
        float nm = fmaxf(mo, mx);
        float corr = exp2f(mo - nm);
        float p0 = exp2f(x0-nm), p1 = exp2f(x1-nm), p2 = exp2f(x2-nm), p3 = exp2f(x3-nm);
        float rs = (p0+p1)+(p2+p3);
#pragma unroll
        for (int off=1; off<16; off<<=1) rs += __shfl_xor(rs, off);
        lrun[m][q] = fmaf(lrun[m][q], corr, rs);
        mrun[m][q] = nm;
        oacc[m][q] *= corr;
        unsigned short* pr = &Pw[(m*16 + g*4 + q)*72];
        pr[r]    = f2bf(p0);
        pr[16+r] = f2bf(p1);
        pr[32+r] = f2bf(p2);
        pr[48+r] = f2bf(p3);
      }
    }

    // PV
    s16x8 bv0 = *(const s16x8*)&VT[r*72 + g*8];
    s16x8 bv1 = *(const s16x8*)&VT[r*72 + 32 + g*8];
#pragma unroll
    for (int m=0;m<4;m++){
      s16x8 pa0 = *(const s16x8*)&Pw[(m*16+r)*72 + g*8];
      s16x8 pa1 = *(const s16x8*)&Pw[(m*16+r)*72 + 32 + g*8];
      oacc[m] = MFMA(pa0, bv0, oacc[m]);
      oacc[m] = MFMA(pa1, bv1, oacc[m]);
    }
  }

  float* pp = part + (size_t)(bh*nsplit + split)*(LS_*18);
#pragma unroll
  for (int m=0;m<4;m++)
#pragma unroll
    for (int q=0;q<4;q++){
      int row = wv*64 + m*16 + g*4 + q;
      if (r == 0){ pp[row] = mrun[m][q]; pp[LS_ + row] = lrun[m][q]; }
      pp[(2+r)*LS_ + row] = oacc[m][q];
    }
}

__global__ __launch_bounds__(256) void attn_combine_k(
    const float* __restrict__ part, float* __restrict__ O, int nsplit)
{
  const int idx = blockIdx.x*256 + threadIdx.x;
  const int bh = idx >> 8;
  const int l  = idx & 255;
  const int b = bh >> 3, h = bh & 7;
  float M = -1e30f;
  for (int sp=0; sp<nsplit; sp++)
    M = fmaxf(M, part[(size_t)(bh*nsplit+sp)*(LS_*18) + l]);
  float sum = 0.f;
  float acc[16];
#pragma unroll
  for (int d=0; d<16; d++) acc[d]=0.f;
  for (int sp=0; sp<nsplit; sp++) {
    const float* pp = part + (size_t)(bh*nsplit+sp)*(LS_*18);
    float cf = exp2f(pp[l] - M);
    sum = fmaf(pp[LS_+l], cf, sum);
#pragma unroll
    for (int d=0; d<16; d++) acc[d] = fmaf(pp[(2+d)*LS_+l], cf, acc[d]);
  }
  float inv = 1.0f / sum;
  float* op = O + ((size_t)(b*LS_ + l)*INNER_ + h*DH_);
#pragma unroll
  for (int d=0; d<16; d++) op[d] = acc[d]*inv;
}

// ---------------------------------------------------------------------------
// MFMA FFW hidden (64x64 tile, K=128)
// ---------------------------------------------------------------------------
__global__ __launch_bounds__(256) void ffw_hidden_mfma_k(
    const unsigned short* __restrict__ Ab, const unsigned short* __restrict__ W1T,
    const float* __restrict__ b1, unsigned short* __restrict__ Hb, int c0)
{
  __shared__ char smem[48*1024];
  unsigned short* As  = (unsigned short*)smem;
  unsigned short* B1s = (unsigned short*)(smem+16384);
  unsigned short* B2s = (unsigned short*)(smem+32768);
  const int bm = blockIdx.y*64, bn = blockIdx.x*64;
  const int tid = threadIdx.x;
#pragma unroll
  for (int p=0;p<4;p++){
    int e = tid + p*256; int row = e>>4, cb = e&15;
    int sw = (cb ^ (row&7))*16;
    *(s16x8*)((char*)As  + row*256 + sw) = *(const s16x8*)(Ab  + (size_t)(bm+row)*LC_ + cb*8);
    *(s16x8*)((char*)B1s + row*256 + sw) = *(const s16x8*)(W1T + (size_t)(c0+bn+row)*LC_ + cb*8);
    *(s16x8*)((char*)B2s + row*256 + sw) = *(const s16x8*)(W1T + ((size_t)FFH_+c0+bn+row)*LC_ + cb*8);
  }
  __syncthreads();
  const int lane = tid&63, wid = tid>>6;
  const int wr = (wid>>1)*32, wc = (wid&1)*32;
  const int r = lane&15, g = lane>>4;
  f32x4 acc1[2][2], acc2[2][2];
#pragma unroll
  for (int mi=0;mi<2;mi++)
#pragma unroll
    for (int ni=0;ni<2;ni++){ acc1[mi][ni]=(f32x4){0,0,0,0}; acc2[mi][ni]=(f32x4){0,0,0,0}; }
#pragma unroll
  for (int ks=0; ks<4; ks++){
    const int cb = ks*4 + g;
    s16x8 a[2], bf1[2], bf2[2];
#pragma unroll
    for (int mi=0;mi<2;mi++){
      int row = wr+mi*16+r; int sw=(cb^(row&7))*16;
      a[mi] = *(const s16x8*)((const char*)As + row*256 + sw);
    }
#pragma unroll
    for (int ni=0;ni<2;ni++){
      int row = wc+ni*16+r; int sw=(cb^(row&7))*16;
      bf1[ni] = *(const s16x8*)((const char*)B1s + row*256 + sw);
      bf2[ni] = *(const s16x8*)((const char*)B2s + row*256 + sw);
    }
#pragma unroll
    for (int mi=0;mi<2;mi++)
#pragma unroll
      for (int ni=0;ni<2;ni++){
        acc1[mi][ni] = MFMA(a[mi], bf1[ni], acc1[mi][ni]);
        acc2[mi][ni] = MFMA(a[mi], bf2[ni], acc2[mi][ni]);
      }
  }
  __syncthreads();
  unsigned short* Ts = (unsigned short*)smem;   // [64][72]
#pragma unroll
  for (int mi=0;mi<2;mi++)
#pragma unroll
    for (int ni=0;ni<2;ni++)
#pragma unroll
      for (int q=0;q<4;q++){
        int row = wr + mi*16 + g*4 + q;
        int col = wc + ni*16 + r;
        int colg = c0 + bn + col;
        float u1 = acc1[mi][ni][q] + b1[colg];
        float u2 = acc2[mi][ni][q] + b1[FFH_ + colg];
        float ge = 0.5f*u2*(1.0f + erff(u2*0.70710678118654752440f));
        Ts[row*72 + col] = f2bf(u1*ge);
      }
  __syncthreads();
#pragma unroll
  for (int p=0;p<2;p++){
    int e = tid + p*256; int row = e>>3, cb = e&7;
    *(s16x8*)(Hb + (size_t)(bm+row)*CH_ + bn + cb*8) =
        *(const s16x8*)((const char*)Ts + row*144 + cb*16);
  }
}

// ---------------------------------------------------------------------------
// MFMA FFW second GEMM, split-K(256), atomic accumulate into fp32 lat.
// ---------------------------------------------------------------------------
__global__ __launch_bounds__(256) void ffw2_mfma_k(
    const unsigned short* __restrict__ Hb, const unsigned short* __restrict__ W2T,
    float* __restrict__ C, int c0)
{
  __shared__ char smem[24*1024];
  unsigned short* As = (unsigned short*)smem;
  unsigned short* Bs = (unsigned short*)(smem+8192);
  const int bm = blockIdx.y*64;
  const int k0 = blockIdx.x*256;
  const int tid = threadIdx.x;
  const int lane = tid&63, wid = tid>>6;
  const int wr = (wid>>1)*32, wc = (wid&1)*64;
  const int r = lane&15, g = lane>>4;
  f32x4 acc[2][4];
#pragma unroll
  for (int mi=0;mi<2;mi++)
#pragma unroll
    for (int ni=0;ni<4;ni++) acc[mi][ni]=(f32x4){0,0,0,0};

  for (int kb=0; kb<256; kb+=64){
    __syncthreads();
#pragma unroll
    for (int p=0;p<2;p++){
      int e = tid + p*256; int row=e>>3, cb=e&7;
      int sw = (cb ^ (row&7))*16;
      *(s16x8*)((char*)As + row*128 + sw) =
          *(const s16x8*)(Hb + (size_t)(bm+row)*CH_ + k0+kb+cb*8);
    }
#pragma unroll
    for (int p=0;p<4;p++){
      int e = tid + p*256; int row=e>>3, cb=e&7;
      int sw = (cb ^ (row&7))*16;
      *(s16x8*)((char*)Bs + row*128 + sw) =
          *(const s16x8*)(W2T + (size_t)row*FFH_ + c0+k0+kb+cb*8);
    }
    __syncthreads();
#pragma unroll
    for (int ks=0; ks<2; ks++){
      const int cb = ks*4 + g;
      s16x8 a[2], b[4];
#pragma unroll
      for (int mi=0;mi<2;mi++){
        int row = wr+mi*16+r; int sw=(cb^(row&7))*16;
        a[mi] = *(const s16x8*)((const char*)As + row*128 + sw);
      }
#pragma unroll
      for (int ni=0;ni<4;ni++){
        int row = wc+ni*16+r; int sw=(cb^(row&7))*16;
        b[ni] = *(const s16x8*)((const char*)Bs + row*128 + sw);
      }
#pragma unroll
      for (int mi=0;mi<2;mi++)
#pragma unroll
        for (int ni=0;ni<4;ni++)
          acc[mi][ni] = MFMA(a[mi], b[ni], acc[mi][ni]);
    }
  }
#pragma unroll
  for (int mi=0;mi<2;mi++)
#pragma unroll
    for (int ni=0;ni<4;ni++)
#pragma unroll
      for (int q=0;q<4;q++){
        int row = bm + wr + mi*16 + g*4 + q;
        int col = wc + ni*16 + r;
        atomicAdd(&C[(size_t)row*LC_ + col], acc[mi][ni][q]);
      }
}

// ---------------------------------------------------------------------------
// Small kernels
// ---------------------------------------------------------------------------
__global__ __launch_bounds__(256) void bcast_k(const float* __restrict__ src,
                                               float* __restrict__ dst)
{
  int i = blockIdx.x*256 + threadIdx.x;
  dst[i] = src[i & (LS_*LC_ - 1)];
}

// LayerNorm -> bf16 xnb; also lat += b2 (residual bias pre-add)
__global__ __launch_bounds__(256) void ln_b2_k(float* __restrict__ x,
                                               const float* __restrict__ g,
                                               const float* __restrict__ bta,
                                               const float* __restrict__ b2,
                                               unsigned short* __restrict__ yb, int rows)
{
  int w = (blockIdx.x * blockDim.x + threadIdx.x) >> 6;
  int lane = threadIdx.x & 63;
  if (w >= rows) return;
  float* xr = x + (size_t)w*LC_;
  float x0 = xr[lane], x1 = xr[lane+64];
  float s = x0 + x1;
#pragma unroll
  for (int off=32; off; off>>=1) s += __shfl_xor(s, off);
  float mu = s * (1.0f/128.0f);
  float d0 = x0-mu, d1 = x1-mu;
  float v = d0*d0 + d1*d1;
#pragma unroll
  for (int off=32; off; off>>=1) v += __shfl_xor(v, off);
  float rstd = rsqrtf(v*(1.0f/128.0f) + 1e-5f);
  unsigned short* yr = yb + (size_t)w*LC_;
  yr[lane]    = f2bf(d0*rstd*g[lane]    + bta[lane]);
  yr[lane+64] = f2bf(d1*rstd*g[lane+64] + bta[lane+64]);
  xr[lane]    = x0 + b2[lane];
  xr[lane+64] = x1 + b2[lane+64];
}

// ---------------------------------------------------------------------------
static inline void gemm_f(hipStream_t s, const float* A,int lda,const float* Bm,int ldb,
    float* C,int ldc,const float* bias,const float* res,float alpha,float beta,
    int M,int N,int K)
{
  GemmP p; p.A=A;p.Bm=Bm;p.C=C;p.bias=bias;p.res=res;p.lda=lda;p.ldb=ldb;p.ldc=ldc;
  p.alpha=alpha;p.beta=beta;p.K=K;
  hipLaunchKernelGGL((gemm_k<32,32,16,2,2,false>), dim3(N/32,M/32,1), dim3(256), 0, s, p);
}
static inline void gemm_b(hipStream_t s, const float* A,int lda,const float* Bm,int ldb,
    unsigned short* C,int ldc,int M,int N,int K)
{
  GemmP p; p.A=A;p.Bm=Bm;p.C=C;p.bias=nullptr;p.res=nullptr;p.lda=lda;p.ldb=ldb;p.ldc=ldc;
  p.alpha=1.f;p.beta=0.f;p.K=K;
  if (M >= 2048)
    hipLaunchKernelGGL((gemm_k<64,64,16,4,4,true>), dim3(N/64,M/64,1), dim3(256), 0, s, p);
  else
    hipLaunchKernelGGL((gemm_k<32,32,16,2,2,true>), dim3(N/32,M/32,1), dim3(256), 0, s, p);
}

extern "C" void kernel_launch(void* const* d_in, const int* in_sizes, int n_in,
                              void* d_out, int out_size, void* d_ws, size_t ws_size,
                              hipStream_t stream)
{
  (void)in_sizes; (void)n_in; (void)out_size; (void)ws_size;
  const float* data    = (const float*)d_in[0];
  const float* inilat  = (const float*)d_in[1];
  const float* ca_Wq   = (const float*)d_in[2];
  const float* ca_Wk   = (const float*)d_in[3];
  const float* ca_Wv   = (const float*)d_in[4];
  const float* ca_Wo   = (const float*)d_in[5];
  const float* ca_bo   = (const float*)d_in[6];
  const float* tr_Wq   = (const float*)d_in[7];
  const float* tr_Wk   = (const float*)d_in[8];
  const float* tr_Wv   = (const float*)d_in[9];
  const float* tr_Wo   = (const float*)d_in[10];
  const float* tr_bo   = (const float*)d_in[11];
  const float* caff_g  = (const float*)d_in[12];
  const float* caff_b  = (const float*)d_in[13];
  const float* caff_W1 = (const float*)d_in[14];
  const float* caff_b1 = (const float*)d_in[15];
  const float* caff_W2 = (const float*)d_in[16];
  const float* caff_b2 = (const float*)d_in[17];
  const float* trff_g  = (const float*)d_in[18];
  const float* trff_b  = (const float*)d_in[19];
  const float* trff_W1 = (const float*)d_in[20];
  const float* trff_b1 = (const float*)d_in[21];
  const float* trff_W2 = (const float*)d_in[22];
  const float* trff_b2 = (const float*)d_in[23];

  float* ws  = (float*)d_ws;
  float* lat = ws;                       // 131072
  float* Ob  = lat + LATSZ_;             // 131072
  float* zb  = Ob + LATSZ_;              // 131072
  unsigned short* Qbf  = (unsigned short*)(zb + LATSZ_);   // 131072 sh = 65536 f
  unsigned short* Klbf = Qbf + LATSZ_;
  unsigned short* Vlbf = Klbf + LATSZ_;
  unsigned short* xnb  = Vlbf + LATSZ_;
  unsigned short* Kdbf = xnb + LATSZ_;                     // B*DS*INNER = 4.19M sh
  unsigned short* Vdbf = Kdbf + (size_t)B_*DS_*INNER_;
  float* part = (float*)(Vdbf + (size_t)B_*DS_*INNER_);    // 32*16*256*18 f
  unsigned short* W1Tc = (unsigned short*)(part + (size_t)B_*H_*NSPL_CROSS*LS_*18);
  unsigned short* W1Tt = W1Tc + (size_t)2*FFH_*LC_;
  unsigned short* W2Tc = W1Tt + (size_t)2*FFH_*LC_;
  unsigned short* W2Tt = W2Tc + (size_t)FFH_*LC_;
  unsigned short* hb   = W2Tt + (size_t)FFH_*LC_;          // 1024*CH_ sh

  // weight conversions (bf16 B^T layout)
  hipLaunchKernelGGL(cvtT_k, dim3(2*FFH_/32, LC_/32), dim3(256), 0, stream, caff_W1, W1Tc, LC_, 2*FFH_);
  hipLaunchKernelGGL(cvtT_k, dim3(2*FFH_/32, LC_/32), dim3(256), 0, stream, trff_W1, W1Tt, LC_, 2*FFH_);
  hipLaunchKernelGGL(cvtT_k, dim3(LC_/32, FFH_/32), dim3(256), 0, stream, caff_W2, W2Tc, FFH_, LC_);
  hipLaunchKernelGGL(cvtT_k, dim3(LC_/32, FFH_/32), dim3(256), 0, stream, trff_W2, W2Tt, FFH_, LC_);

  hipLaunchKernelGGL(bcast_k, dim3(LATSZ_/256), dim3(256), 0, stream, inilat, lat);
  gemm_b(stream, data, DC_, ca_Wk, INNER_, Kdbf, INNER_, B_*DS_, INNER_, DC_);
  gemm_b(stream, data, DC_, ca_Wv, INNER_, Vdbf, INNER_, B_*DS_, INNER_, DC_);

  auto cross_attend = [&](float alpha, float beta) {
    gemm_b(stream, lat, LC_, ca_Wq, INNER_, Qbf, INNER_, NLAT_, INNER_, LC_);
    hipLaunchKernelGGL(flash_k, dim3(B_*H_*NSPL_CROSS), dim3(256), 0, stream,
                       Qbf, Kdbf, Vdbf, part, DS_, NSPL_CROSS);
    hipLaunchKernelGGL(attn_combine_k, dim3(B_*H_*LS_/256), dim3(256), 0, stream, part, Ob, NSPL_CROSS);
    gemm_f(stream, Ob, INNER_, ca_Wo, LC_, lat, LC_, ca_bo, lat, alpha, beta, NLAT_, LC_, INNER_);
  };

  auto self_layer = [&](const float* in, float* out, int t, float alpha, float beta, const float* res) {
    hipLaunchKernelGGL((gemm_qkv_k<32,32,16,2,2>), dim3(INNER_/32, NLAT_/32, 3), dim3(256), 0, stream,
        in, LC_,
        tr_Wq + (size_t)t*LC_*INNER_, tr_Wk + (size_t)t*LC_*INNER_, tr_Wv + (size_t)t*LC_*INNER_,
        INNER_, Qbf, Klbf, Vlbf, INNER_, LC_);
    hipLaunchKernelGGL(flash_k, dim3(B_*H_*NSPL_SELF), dim3(256), 0, stream,
                       Qbf, Klbf, Vlbf, part, LS_, NSPL_SELF);
    hipLaunchKernelGGL(attn_combine_k, dim3(B_*H_*LS_/256), dim3(256), 0, stream, part, Ob, NSPL_SELF);
    gemm_f(stream, Ob, INNER_, tr_Wo + (size_t)t*INNER_*LC_, LC_, out, LC_,
           tr_bo + (size_t)t*LC_, res, alpha, beta, NLAT_, LC_, INNER_);
  };

  auto ffw = [&](const float* g, const float* bta,
                 const unsigned short* W1T, const float* b1,
                 const unsigned short* W2T, const float* b2) {
    hipLaunchKernelGGL(ln_b2_k, dim3(NLAT_/4), dim3(256), 0, stream, lat, g, bta, b2, xnb, NLAT_);
    for (int c0 = 0; c0 < FFH_; c0 += CH_) {
      hipLaunchKernelGGL(ffw_hidden_mfma_k, dim3(CH_/64, NLAT_/64), dim3(256), 0, stream,
                         xnb, W1T, b1, hb, c0);
      hipLaunchKernelGGL(ffw2_mfma_k, dim3(CH_/256, NLAT_/64), dim3(256), 0, stream,
                         hb, W2T, lat, c0);
    }
  };

  cross_attend(1.f, 0.f);
  self_layer(lat, zb, 0, 1.f, 0.f, nullptr);
  self_layer(zb, lat, 1, 1.f, 0.f, nullptr);

  for (int na = 0; na < 2; na++) {
    cross_attend(0.5f, 0.5f);
    ffw(caff_g, caff_b, W1Tc, caff_b1, W2Tc, caff_b2);
    self_layer(lat, zb, 0, 1.f, 0.f, nullptr);
    self_layer(zb, lat, 1, 0.5f, 0.5f, lat);
    ffw(trff_g, trff_b, W1Tt, trff_b1, W2Tt, trff_b2);
  }

  hipMemcpyAsync(d_out, lat, (size_t)LATSZ_*sizeof(float), hipMemcpyDeviceToDevice, stream);
}

// Round 6
// 897.552 us; speedup vs baseline: 3.1728x; 1.1523x over previous
//
#include <hip/hip_runtime.h>
#include <math.h>

#define B_ 4
#define DS_ 8192
#define DC_ 64
#define LS_ 256
#define LC_ 128
#define H_ 8
#define DH_ 16
#define INNER_ 128
#define FFH_ 16384
#define NLAT_ (B_*LS_)          // 1024
#define LATSZ_ (B_*LS_*LC_)     // 131072
#define NSPL_CROSS 32
#define NSPL_SELF 4
#define CH_ 8192                // FFW column chunk
#define QS_ 0.36067376022224085f   // 16^-0.5 * log2(e), folded into Q

typedef __attribute__((ext_vector_type(8))) short s16x8;
typedef __attribute__((ext_vector_type(4))) float f32x4;

static __device__ __forceinline__ f32x4 MFMA(s16x8 a, s16x8 b, f32x4 c){
  return __builtin_amdgcn_mfma_f32_16x16x32_bf16(a, b, c, 0, 0, 0);
}
static __device__ __forceinline__ unsigned short f2bf(float f){
  unsigned u = __float_as_uint(f);
  return (unsigned short)((u + 0x7fffu + ((u>>16)&1u)) >> 16);
}

// ---------------------------------------------------------------------------
// fp32 tiled GEMM (projections).  C = alpha*(A@B + bias) + beta*res
// ---------------------------------------------------------------------------
struct GemmP {
  const float* A; const float* Bm; void* C;
  const float* bias; const float* res;
  int lda, ldb, ldc;
  float alpha, beta;
  int K;
};

template<int BM,int BN,int BK,int TM,int TN,bool OUTB>
__global__ __launch_bounds__(256) void gemm_k(GemmP p)
{
  __shared__ float As[BK][BM+4];
  __shared__ float Bs[BK][BN+4];
  const int bm = blockIdx.y * BM;
  const int bn = blockIdx.x * BN;
  const int tid = threadIdx.x;
  constexpr int NTX = BN / TN;
  const int tx = tid % NTX;
  const int ty = tid / NTX;
  float acc[TM][TN];
#pragma unroll
  for (int i=0;i<TM;i++)
#pragma unroll
    for (int j=0;j<TN;j++) acc[i][j]=0.f;

  for (int kb=0; kb<p.K; kb+=BK) {
#pragma unroll
    for (int e=tid; e<BM*BK; e+=256) {
      int r=e/BK, c=e%BK;
      As[c][r] = p.A[(size_t)(bm+r)*p.lda + kb + c];
    }
#pragma unroll
    for (int e=tid; e<BK*BN; e+=256) {
      int r=e/BN, c=e%BN;
      Bs[r][c] = p.Bm[(size_t)(kb+r)*p.ldb + bn + c];
    }
    __syncthreads();
#pragma unroll
    for (int kk=0;kk<BK;kk++) {
      float a[TM], b[TN];
#pragma unroll
      for (int i=0;i<TM;i++) a[i]=As[kk][ty*TM+i];
#pragma unroll
      for (int j=0;j<TN;j++) b[j]=Bs[kk][tx*TN+j];
#pragma unroll
      for (int i=0;i<TM;i++)
#pragma unroll
        for (int j=0;j<TN;j++) acc[i][j]=fmaf(a[i],b[j],acc[i][j]);
    }
    __syncthreads();
  }
#pragma unroll
  for (int i=0;i<TM;i++) {
    const size_t row = bm + ty*TM + i;
#pragma unroll
    for (int j=0;j<TN;j++) {
      const int col = bn + tx*TN + j;
      float v = acc[i][j];
      if (p.bias) v += p.bias[col];
      v *= p.alpha;
      if (p.beta != 0.f) v += p.beta * p.res[row*p.ldc + col];
      if (OUTB) ((unsigned short*)p.C)[row*p.ldc + col] = f2bf(v);
      else      ((float*)p.C)[row*p.ldc + col] = v;
    }
  }
}

// Fused Q/K/V self projection: bf16 outputs; Q (z==0) scaled by alphaQ.
template<int BM,int BN,int BK,int TM,int TN>
__global__ __launch_bounds__(256) void gemm_qkv_k(
    const float* __restrict__ A, int lda,
    const float* __restrict__ B0, const float* __restrict__ B1, const float* __restrict__ B2,
    int ldb, unsigned short* C0, unsigned short* C1, unsigned short* C2, int ldc, int K,
    float alphaQ)
{
  const float* Bm = (blockIdx.z==0)?B0:((blockIdx.z==1)?B1:B2);
  unsigned short* C  = (blockIdx.z==0)?C0:((blockIdx.z==1)?C1:C2);
  const float alpha = (blockIdx.z==0)? alphaQ : 1.0f;
  __shared__ float As[BK][BM+4];
  __shared__ float Bs[BK][BN+4];
  const int bm = blockIdx.y * BM;
  const int bn = blockIdx.x * BN;
  const int tid = threadIdx.x;
  constexpr int NTX = BN / TN;
  const int tx = tid % NTX;
  const int ty = tid / NTX;
  float acc[TM][TN];
#pragma unroll
  for (int i=0;i<TM;i++)
#pragma unroll
    for (int j=0;j<TN;j++) acc[i][j]=0.f;
  for (int kb=0; kb<K; kb+=BK) {
#pragma unroll
    for (int e=tid; e<BM*BK; e+=256) {
      int r=e/BK, c=e%BK;
      As[c][r] = A[(size_t)(bm+r)*lda + kb + c];
    }
#pragma unroll
    for (int e=tid; e<BK*BN; e+=256) {
      int r=e/BN, c=e%BN;
      Bs[r][c] = Bm[(size_t)(kb+r)*ldb + bn + c];
    }
    __syncthreads();
#pragma unroll
    for (int kk=0;kk<BK;kk++) {
      float a[TM], b[TN];
#pragma unroll
      for (int i=0;i<TM;i++) a[i]=As[kk][ty*TM+i];
#pragma unroll
      for (int j=0;j<TN;j++) b[j]=Bs[kk][tx*TN+j];
#pragma unroll
      for (int i=0;i<TM;i++)
#pragma unroll
        for (int j=0;j<TN;j++) acc[i][j]=fmaf(a[i],b[j],acc[i][j]);
    }
    __syncthreads();
  }
#pragma unroll
  for (int i=0;i<TM;i++) {
    const size_t row = bm + ty*TM + i;
#pragma unroll
    for (int j=0;j<TN;j++)
      C[row*ldc + bn + tx*TN + j] = f2bf(acc[i][j]*alpha);
  }
}

// ---------------------------------------------------------------------------
// Convert+transpose fp32 W[K][N] -> bf16 WT[N][K]
// ---------------------------------------------------------------------------
__global__ __launch_bounds__(256) void cvtT_k(const float* __restrict__ W,
                                              unsigned short* __restrict__ WT,
                                              int K, int N)
{
  __shared__ unsigned short t[32][33];
  const int kb = blockIdx.y*32, nb = blockIdx.x*32;
  const int tx = threadIdx.x & 31, ty = threadIdx.x >> 5;
#pragma unroll
  for (int i = ty; i < 32; i += 8)
    t[i][tx] = f2bf(W[(size_t)(kb+i)*N + nb + tx]);
  __syncthreads();
#pragma unroll
  for (int i = ty; i < 32; i += 8)
    WT[(size_t)(nb+i)*K + kb + tx] = t[tx][i];
}

// ---------------------------------------------------------------------------
// Flash MFMA attention partials — NO-MAX variant.
// Logits here are provably small (|QK|*scale << 1), so softmax is computed
// as exp2(S)/sum without running-max: linear accumulation, no rescale, no
// in-loop cross-lane ops.  Q comes in pre-scaled by 16^-0.5*log2(e).
// One block per (bh,split), 4 waves x 64 latent rows.
// part[(bh*nsplit+split)]: SoA {unused[256], den[256], acc[16][256]}
// ---------------------------------------------------------------------------
__global__ __launch_bounds__(256, 4) void flash_k(
    const unsigned short* __restrict__ Qb, const unsigned short* __restrict__ Kb,
    const unsigned short* __restrict__ Vb, float* __restrict__ part,
    int S, int nsplit)
{
  __shared__ __align__(16) char smem[25856];
  unsigned short* Ks = (unsigned short*)smem;                 // [64][40]
  unsigned short* VT = (unsigned short*)(smem + 5120);        // [16][72], col^=(row&8)
  const int tid = threadIdx.x, lane = tid & 63, wv = tid >> 6;
  // per-wave, per-parity P tile [16][72], c_off ^= (row&8)<<1
  unsigned short* Pw0 = (unsigned short*)(smem + 7424) + wv*2304;
  unsigned short* Pw1 = Pw0 + 1152;   // shorts: 2304B

  const int blk = blockIdx.x;
  const int split = blk % nsplit, bh = blk / nsplit;
  const int b = bh >> 3, h = bh & 7;
  const int r = lane & 15, g = lane >> 4;

  // zero K-dim pad (cols 16..31)
  {
    int t0 = tid >> 2, c0 = (tid & 3) * 4;
    *(ushort4*)&Ks[t0*40 + 16 + c0] = (ushort4){0,0,0,0};
  }

  // Q a-frags (K padded to 32; g>=2 lanes zero)
  s16x8 qa[4];
#pragma unroll
  for (int m=0;m<4;m++){
    if (g < 2)
      qa[m] = *(const s16x8*)(Qb + ((size_t)(b*LS_) + wv*64 + m*16 + r)*INNER_ + h*DH_ + g*8);
    else
      qa[m] = (s16x8){0,0,0,0,0,0,0,0};
  }

  f32x4 oacc[4];
  float den[4][4];
#pragma unroll
  for (int m=0;m<4;m++){
    oacc[m] = (f32x4){0,0,0,0};
#pragma unroll
    for (int q=0;q<4;q++) den[m][q] = 0.f;
  }

  const int len = S / nsplit, s0 = split * len;
  const int xs = (g & 2) << 3;            // P-store column swizzle (0 or 16)
  const int gx = g ^ (((r>>3)&1)<<1);     // P-read swizzle
  const int gv = g ^ ((r>>3)&1);          // V-read swizzle

  for (int sc = s0; sc < s0 + len; sc += 64) {
    __syncthreads();
    {
      int t0 = tid >> 2, c0 = (tid & 3) * 4;
      size_t base = ((size_t)(b)*S + sc + t0)*INNER_ + h*DH_ + c0;
      ushort4 kv = *(const ushort4*)(Kb + base);
      *(ushort4*)&Ks[t0*40 + c0] = kv;
      ushort4 vv = *(const ushort4*)(Vb + base);
      VT[(c0+0)*72 + (t0 ^ ((c0+0)&8))] = vv.x;
      VT[(c0+1)*72 + (t0 ^ ((c0+1)&8))] = vv.y;
      VT[(c0+2)*72 + (t0 ^ ((c0+2)&8))] = vv.z;
      VT[(c0+3)*72 + (t0 ^ ((c0+3)&8))] = vv.w;
    }
    __syncthreads();

    s16x8 bk[4];
#pragma unroll
    for (int n=0;n<4;n++) bk[n] = *(const s16x8*)&Ks[(n*16+r)*40 + g*8];
    s16x8 bv0 = *(const s16x8*)&VT[r*72 + gv*8];
    s16x8 bv1 = *(const s16x8*)&VT[r*72 + 32 + gv*8];

#pragma unroll
    for (int m=0;m<4;m++){
      f32x4 sv[4];
#pragma unroll
      for (int n=0;n<4;n++) sv[n] = MFMA(qa[m], bk[n], (f32x4){0,0,0,0});
      unsigned short* Pw = (m & 1) ? Pw1 : Pw0;
#pragma unroll
      for (int q=0;q<4;q++){
        float p0 = exp2f(sv[0][q]);
        float p1 = exp2f(sv[1][q]);
        float p2 = exp2f(sv[2][q]);
        float p3 = exp2f(sv[3][q]);
        den[m][q] += (p0+p1)+(p2+p3);
        unsigned short* pr = &Pw[(g*4+q)*72];
        pr[( 0^xs)+r] = f2bf(p0);
        pr[(16^xs)+r] = f2bf(p1);
        pr[(32^xs)+r] = f2bf(p2);
        pr[(48^xs)+r] = f2bf(p3);
      }
      s16x8 pa0 = *(const s16x8*)&Pw[r*72 + gx*8];
      s16x8 pa1 = *(const s16x8*)&Pw[r*72 + 32 + gx*8];
      oacc[m] = MFMA(pa0, bv0, oacc[m]);
      oacc[m] = MFMA(pa1, bv1, oacc[m]);
    }
  }

  // one-time den reduction over the 16 column-lanes
#pragma unroll
  for (int m=0;m<4;m++)
#pragma unroll
    for (int q=0;q<4;q++){
      float d = den[m][q];
#pragma unroll
      for (int off=1; off<16; off<<=1) d += __shfl_xor(d, off);
      den[m][q] = d;
    }

  float* pp = part + (size_t)(bh*nsplit + split)*(LS_*18);
#pragma unroll
  for (int m=0;m<4;m++)
#pragma unroll
    for (int q=0;q<4;q++){
      int row = wv*64 + m*16 + g*4 + q;
      if (r == 0) pp[LS_ + row] = den[m][q];
      pp[(2+r)*LS_ + row] = oacc[m][q];
    }
}

__global__ __launch_bounds__(256) void attn_combine_k(
    const float* __restrict__ part, float* __restrict__ O, int nsplit)
{
  const int idx = blockIdx.x*256 + threadIdx.x;
  const int bh = idx >> 8;
  const int l  = idx & 255;
  const int b = bh >> 3, h = bh & 7;
  float sum = 0.f;
  float acc[16];
#pragma unroll
  for (int d=0; d<16; d++) acc[d]=0.f;
  for (int sp=0; sp<nsplit; sp++) {
    const float* pp = part + (size_t)(bh*nsplit+sp)*(LS_*18);
    sum += pp[LS_+l];
#pragma unroll
    for (int d=0; d<16; d++) acc[d] += pp[(2+d)*LS_+l];
  }
  float inv = 1.0f / sum;
  float* op = O + ((size_t)(b*LS_ + l)*INNER_ + h*DH_);
#pragma unroll
  for (int d=0; d<16; d++) op[d] = acc[d]*inv;
}

// ---------------------------------------------------------------------------
// MFMA FFW hidden (64x64 tile, K=128)
// ---------------------------------------------------------------------------
__global__ __launch_bounds__(256) void ffw_hidden_mfma_k(
    const unsigned short* __restrict__ Ab, const unsigned short* __restrict__ W1T,
    const float* __restrict__ b1, unsigned short* __restrict__ Hb, int c0)
{
  __shared__ char smem[48*1024];
  unsigned short* As  = (unsigned short*)smem;
  unsigned short* B1s = (unsigned short*)(smem+16384);
  unsigned short* B2s = (unsigned short*)(smem+32768);
  const int bm = blockIdx.y*64, bn = blockIdx.x*64;
  const int tid = threadIdx.x;
#pragma unroll
  for (int p=0;p<4;p++){
    int e = tid + p*256; int row = e>>4, cb = e&15;
    int sw = (cb ^ (row&7))*16;
    *(s16x8*)((char*)As  + row*256 + sw) = *(const s16x8*)(Ab  + (size_t)(bm+row)*LC_ + cb*8);
    *(s16x8*)((char*)B1s + row*256 + sw) = *(const s16x8*)(W1T + (size_t)(c0+bn+row)*LC_ + cb*8);
    *(s16x8*)((char*)B2s + row*256 + sw) = *(const s16x8*)(W1T + ((size_t)FFH_+c0+bn+row)*LC_ + cb*8);
  }
  __syncthreads();
  const int lane = tid&63, wid = tid>>6;
  const int wr = (wid>>1)*32, wc = (wid&1)*32;
  const int r = lane&15, g = lane>>4;
  f32x4 acc1[2][2], acc2[2][2];
#pragma unroll
  for (int mi=0;mi<2;mi++)
#pragma unroll
    for (int ni=0;ni<2;ni++){ acc1[mi][ni]=(f32x4){0,0,0,0}; acc2[mi][ni]=(f32x4){0,0,0,0}; }
#pragma unroll
  for (int ks=0; ks<4; ks++){
    const int cb = ks*4 + g;
    s16x8 a[2], bf1[2], bf2[2];
#pragma unroll
    for (int mi=0;mi<2;mi++){
      int row = wr+mi*16+r; int sw=(cb^(row&7))*16;
      a[mi] = *(const s16x8*)((const char*)As + row*256 + sw);
    }
#pragma unroll
    for (int ni=0;ni<2;ni++){
      int row = wc+ni*16+r; int sw=(cb^(row&7))*16;
      bf1[ni] = *(const s16x8*)((const char*)B1s + row*256 + sw);
      bf2[ni] = *(const s16x8*)((const char*)B2s + row*256 + sw);
    }
#pragma unroll
    for (int mi=0;mi<2;mi++)
#pragma unroll
      for (int ni=0;ni<2;ni++){
        acc1[mi][ni] = MFMA(a[mi], bf1[ni], acc1[mi][ni]);
        acc2[mi][ni] = MFMA(a[mi], bf2[ni], acc2[mi][ni]);
      }
  }
  __syncthreads();
  unsigned short* Ts = (unsigned short*)smem;   // [64][72]
#pragma unroll
  for (int mi=0;mi<2;mi++)
#pragma unroll
    for (int ni=0;ni<2;ni++)
#pragma unroll
      for (int q=0;q<4;q++){
        int row = wr + mi*16 + g*4 + q;
        int col = wc + ni*16 + r;
        int colg = c0 + bn + col;
        float u1 = acc1[mi][ni][q] + b1[colg];
        float u2 = acc2[mi][ni][q] + b1[FFH_ + colg];
        float ge = 0.5f*u2*(1.0f + erff(u2*0.70710678118654752440f));
        Ts[row*72 + col] = f2bf(u1*ge);
      }
  __syncthreads();
#pragma unroll
  for (int p=0;p<2;p++){
    int e = tid + p*256; int row = e>>3, cb = e&7;
    *(s16x8*)(Hb + (size_t)(bm+row)*CH_ + bn + cb*8) =
        *(const s16x8*)((const char*)Ts + row*144 + cb*16);
  }
}

// ---------------------------------------------------------------------------
// MFMA FFW second GEMM, split-K(256), atomic accumulate into fp32 lat.
// ---------------------------------------------------------------------------
__global__ __launch_bounds__(256) void ffw2_mfma_k(
    const unsigned short* __restrict__ Hb, const unsigned short* __restrict__ W2T,
    float* __restrict__ C, int c0)
{
  __shared__ char smem[24*1024];
  unsigned short* As = (unsigned short*)smem;
  unsigned short* Bs = (unsigned short*)(smem+8192);
  const int bm = blockIdx.y*64;
  const int k0 = blockIdx.x*256;
  const int tid = threadIdx.x;
  const int lane = tid&63, wid = tid>>6;
  const int wr = (wid>>1)*32, wc = (wid&1)*64;
  const int r = lane&15, g = lane>>4;
  f32x4 acc[2][4];
#pragma unroll
  for (int mi=0;mi<2;mi++)
#pragma unroll
    for (int ni=0;ni<4;ni++) acc[mi][ni]=(f32x4){0,0,0,0};

  for (int kb=0; kb<256; kb+=64){
    __syncthreads();
#pragma unroll
    for (int p=0;p<2;p++){
      int e = tid + p*256; int row=e>>3, cb=e&7;
      int sw = (cb ^ (row&7))*16;
      *(s16x8*)((char*)As + row*128 + sw) =
          *(const s16x8*)(Hb + (size_t)(bm+row)*CH_ + k0+kb+cb*8);
    }
#pragma unroll
    for (int p=0;p<4;p++){
      int e = tid + p*256; int row=e>>3, cb=e&7;
      int sw = (cb ^ (row&7))*16;
      *(s16x8*)((char*)Bs + row*128 + sw) =
          *(const s16x8*)(W2T + (size_t)row*FFH_ + c0+k0+kb+cb*8);
    }
    __syncthreads();
#pragma unroll
    for (int ks=0; ks<2; ks++){
      const int cb = ks*4 + g;
      s16x8 a[2], b[4];
#pragma unroll
      for (int mi=0;mi<2;mi++){
        int row = wr+mi*16+r; int sw=(cb^(row&7))*16;
        a[mi] = *(const s16x8*)((const char*)As + row*128 + sw);
      }
#pragma unroll
      for (int ni=0;ni<4;ni++){
        int row = wc+ni*16+r; int sw=(cb^(row&7))*16;
        b[ni] = *(const s16x8*)((const char*)Bs + row*128 + sw);
      }
#pragma unroll
      for (int mi=0;mi<2;mi++)
#pragma unroll
        for (int ni=0;ni<4;ni++)
          acc[mi][ni] = MFMA(a[mi], b[ni], acc[mi][ni]);
    }
  }
#pragma unroll
  for (int mi=0;mi<2;mi++)
#pragma unroll
    for (int ni=0;ni<4;ni++)
#pragma unroll
      for (int q=0;q<4;q++){
        int row = bm + wr + mi*16 + g*4 + q;
        int col = wc + ni*16 + r;
        atomicAdd(&C[(size_t)row*LC_ + col], acc[mi][ni][q]);
      }
}

// ---------------------------------------------------------------------------
// Small kernels
// ---------------------------------------------------------------------------
__global__ __launch_bounds__(256) void bcast_k(const float* __restrict__ src,
                                               float* __restrict__ dst)
{
  int i = blockIdx.x*256 + threadIdx.x;
  dst[i] = src[i & (LS_*LC_ - 1)];
}

// LayerNorm -> bf16 xnb; also lat += b2 (residual bias pre-add)
__global__ __launch_bounds__(256) void ln_b2_k(float* __restrict__ x,
                                               const float* __restrict__ g,
                                               const float* __restrict__ bta,
                                               const float* __restrict__ b2,
                                               unsigned short* __restrict__ yb, int rows)
{
  int w = (blockIdx.x * blockDim.x + threadIdx.x) >> 6;
  int lane = threadIdx.x & 63;
  if (w >= rows) return;
  float* xr = x + (size_t)w*LC_;
  float x0 = xr[lane], x1 = xr[lane+64];
  float s = x0 + x1;
#pragma unroll
  for (int off=32; off; off>>=1) s += __shfl_xor(s, off);
  float mu = s * (1.0f/128.0f);
  float d0 = x0-mu, d1 = x1-mu;
  float v = d0*d0 + d1*d1;
#pragma unroll
  for (int off=32; off; off>>=1) v += __shfl_xor(v, off);
  float rstd = rsqrtf(v*(1.0f/128.0f) + 1e-5f);
  unsigned short* yr = yb + (size_t)w*LC_;
  yr[lane]    = f2bf(d0*rstd*g[lane]    + bta[lane]);
  yr[lane+64] = f2bf(d1*rstd*g[lane+64] + bta[lane+64]);
  xr[lane]    = x0 + b2[lane];
  xr[lane+64] = x1 + b2[lane+64];
}

// ---------------------------------------------------------------------------
static inline void gemm_f(hipStream_t s, const float* A,int lda,const float* Bm,int ldb,
    float* C,int ldc,const float* bias,const float* res,float alpha,float beta,
    int M,int N,int K)
{
  GemmP p; p.A=A;p.Bm=Bm;p.C=C;p.bias=bias;p.res=res;p.lda=lda;p.ldb=ldb;p.ldc=ldc;
  p.alpha=alpha;p.beta=beta;p.K=K;
  hipLaunchKernelGGL((gemm_k<32,32,16,2,2,false>), dim3(N/32,M/32,1), dim3(256), 0, s, p);
}
static inline void gemm_b(hipStream_t s, const float* A,int lda,const float* Bm,int ldb,
    unsigned short* C,int ldc,int M,int N,int K, float alpha)
{
  GemmP p; p.A=A;p.Bm=Bm;p.C=C;p.bias=nullptr;p.res=nullptr;p.lda=lda;p.ldb=ldb;p.ldc=ldc;
  p.alpha=alpha;p.beta=0.f;p.K=K;
  if (M >= 2048)
    hipLaunchKernelGGL((gemm_k<64,64,16,4,4,true>), dim3(N/64,M/64,1), dim3(256), 0, s, p);
  else
    hipLaunchKernelGGL((gemm_k<32,32,16,2,2,true>), dim3(N/32,M/32,1), dim3(256), 0, s, p);
}

extern "C" void kernel_launch(void* const* d_in, const int* in_sizes, int n_in,
                              void* d_out, int out_size, void* d_ws, size_t ws_size,
                              hipStream_t stream)
{
  (void)in_sizes; (void)n_in; (void)out_size; (void)ws_size;
  const float* data    = (const float*)d_in[0];
  const float* inilat  = (const float*)d_in[1];
  const float* ca_Wq   = (const float*)d_in[2];
  const float* ca_Wk   = (const float*)d_in[3];
  const float* ca_Wv   = (const float*)d_in[4];
  const float* ca_Wo   = (const float*)d_in[5];
  const float* ca_bo   = (const float*)d_in[6];
  const float* tr_Wq   = (const float*)d_in[7];
  const float* tr_Wk   = (const float*)d_in[8];
  const float* tr_Wv   = (const float*)d_in[9];
  const float* tr_Wo   = (const float*)d_in[10];
  const float* tr_bo   = (const float*)d_in[11];
  const float* caff_g  = (const float*)d_in[12];
  const float* caff_b  = (const float*)d_in[13];
  const float* caff_W1 = (const float*)d_in[14];
  const float* caff_b1 = (const float*)d_in[15];
  const float* caff_W2 = (const float*)d_in[16];
  const float* caff_b2 = (const float*)d_in[17];
  const float* trff_g  = (const float*)d_in[18];
  const float* trff_b  = (const float*)d_in[19];
  const float* trff_W1 = (const float*)d_in[20];
  const float* trff_b1 = (const float*)d_in[21];
  const float* trff_W2 = (const float*)d_in[22];
  const float* trff_b2 = (const float*)d_in[23];

  float* ws  = (float*)d_ws;
  float* lat = ws;                       // 131072
  float* Ob  = lat + LATSZ_;             // 131072
  float* zb  = Ob + LATSZ_;              // 131072
  unsigned short* Qbf  = (unsigned short*)(zb + LATSZ_);
  unsigned short* Klbf = Qbf + LATSZ_;
  unsigned short* Vlbf = Klbf + LATSZ_;
  unsigned short* xnb  = Vlbf + LATSZ_;
  unsigned short* Kdbf = xnb + LATSZ_;                     // B*DS*INNER
  unsigned short* Vdbf = Kdbf + (size_t)B_*DS_*INNER_;
  float* part = (float*)(Vdbf + (size_t)B_*DS_*INNER_);
  unsigned short* W1Tc = (unsigned short*)(part + (size_t)B_*H_*NSPL_CROSS*LS_*18);
  unsigned short* W1Tt = W1Tc + (size_t)2*FFH_*LC_;
  unsigned short* W2Tc = W1Tt + (size_t)2*FFH_*LC_;
  unsigned short* W2Tt = W2Tc + (size_t)FFH_*LC_;
  unsigned short* hb   = W2Tt + (size_t)FFH_*LC_;          // 1024*CH_

  // weight conversions (bf16 B^T layout)
  hipLaunchKernelGGL(cvtT_k, dim3(2*FFH_/32, LC_/32), dim3(256), 0, stream, caff_W1, W1Tc, LC_, 2*FFH_);
  hipLaunchKernelGGL(cvtT_k, dim3(2*FFH_/32, LC_/32), dim3(256), 0, stream, trff_W1, W1Tt, LC_, 2*FFH_);
  hipLaunchKernelGGL(cvtT_k, dim3(LC_/32, FFH_/32), dim3(256), 0, stream, caff_W2, W2Tc, FFH_, LC_);
  hipLaunchKernelGGL(cvtT_k, dim3(LC_/32, FFH_/32), dim3(256), 0, stream, trff_W2, W2Tt, FFH_, LC_);

  hipLaunchKernelGGL(bcast_k, dim3(LATSZ_/256), dim3(256), 0, stream, inilat, lat);
  gemm_b(stream, data, DC_, ca_Wk, INNER_, Kdbf, INNER_, B_*DS_, INNER_, DC_, 1.f);
  gemm_b(stream, data, DC_, ca_Wv, INNER_, Vdbf, INNER_, B_*DS_, INNER_, DC_, 1.f);

  auto cross_attend = [&](float alpha, float beta) {
    gemm_b(stream, lat, LC_, ca_Wq, INNER_, Qbf, INNER_, NLAT_, INNER_, LC_, QS_);
    hipLaunchKernelGGL(flash_k, dim3(B_*H_*NSPL_CROSS), dim3(256), 0, stream,
                       Qbf, Kdbf, Vdbf, part, DS_, NSPL_CROSS);
    hipLaunchKernelGGL(attn_combine_k, dim3(B_*H_*LS_/256), dim3(256), 0, stream, part, Ob, NSPL_CROSS);
    gemm_f(stream, Ob, INNER_, ca_Wo, LC_, lat, LC_, ca_bo, lat, alpha, beta, NLAT_, LC_, INNER_);
  };

  auto self_layer = [&](const float* in, float* out, int t, float alpha, float beta, const float* res) {
    hipLaunchKernelGGL((gemm_qkv_k<32,32,16,2,2>), dim3(INNER_/32, NLAT_/32, 3), dim3(256), 0, stream,
        in, LC_,
        tr_Wq + (size_t)t*LC_*INNER_, tr_Wk + (size_t)t*LC_*INNER_, tr_Wv + (size_t)t*LC_*INNER_,
        INNER_, Qbf, Klbf, Vlbf, INNER_, LC_, QS_);
    hipLaunchKernelGGL(flash_k, dim3(B_*H_*NSPL_SELF), dim3(256), 0, stream,
                       Qbf, Klbf, Vlbf, part, LS_, NSPL_SELF);
    hipLaunchKernelGGL(attn_combine_k, dim3(B_*H_*LS_/256), dim3(256), 0, stream, part, Ob, NSPL_SELF);
    gemm_f(stream, Ob, INNER_, tr_Wo + (size_t)t*INNER_*LC_, LC_, out, LC_,
           tr_bo + (size_t)t*LC_, res, alpha, beta, NLAT_, LC_, INNER_);
  };

  auto ffw = [&](const float* g, const float* bta,
                 const unsigned short* W1T, const float* b1,
                 const unsigned short* W2T, const float* b2) {
    hipLaunchKernelGGL(ln_b2_k, dim3(NLAT_/4), dim3(256), 0, stream, lat, g, bta, b2, xnb, NLAT_);
    for (int c0 = 0; c0 < FFH_; c0 += CH_) {
      hipLaunchKernelGGL(ffw_hidden_mfma_k, dim3(CH_/64, NLAT_/64), dim3(256), 0, stream,
                         xnb, W1T, b1, hb, c0);
      hipLaunchKernelGGL(ffw2_mfma_k, dim3(CH_/256, NLAT_/64), dim3(256), 0, stream,
                         hb, W2T, lat, c0);
    }
  };

  cross_attend(1.f, 0.f);
  self_layer(lat, zb, 0, 1.f, 0.f, nullptr);
  self_layer(zb, lat, 1, 1.f, 0.f, nullptr);

  for (int na = 0; na < 2; na++) {
    cross_attend(0.5f, 0.5f);
    ffw(caff_g, caff_b, W1Tc, caff_b1, W2Tc, caff_b2);
    self_layer(lat, zb, 0, 1.f, 0.f, nullptr);
    self_layer(zb, lat, 1, 0.5f, 0.5f, lat);
    ffw(trff_g, trff_b, W1Tt, trff_b1, W2Tt, trff_b2);
  }

  hipMemcpyAsync(d_out, lat, (size_t)LATSZ_*sizeof(float), hipMemcpyDeviceToDevice, stream);
}

// Round 9
// 712.158 us; speedup vs baseline: 3.9988x; 1.2603x over previous
//
#include <hip/hip_runtime.h>
#include <math.h>

#define B_ 4
#define DS_ 8192
#define DC_ 64
#define LS_ 256
#define LC_ 128
#define H_ 8
#define DH_ 16
#define INNER_ 128
#define FFH_ 16384
#define NLAT_ (B_*LS_)          // 1024
#define LATSZ_ (B_*LS_*LC_)     // 131072
#define NSPL_CROSS 32
#define NSPL_SELF 4
#define CH_ 16384               // FFW single chunk
#define QS_ 0.36067376022224085f   // 16^-0.5 * log2(e), folded into Q

typedef __attribute__((ext_vector_type(8))) short s16x8;
typedef __attribute__((ext_vector_type(4))) float f32x4;

static __device__ __forceinline__ f32x4 MFMA(s16x8 a, s16x8 b, f32x4 c){
  return __builtin_amdgcn_mfma_f32_16x16x32_bf16(a, b, c, 0, 0, 0);
}
static __device__ __forceinline__ unsigned short f2bf(float f){
  unsigned u = __float_as_uint(f);
  return (unsigned short)((u + 0x7fffu + ((u>>16)&1u)) >> 16);
}

// ---------------------------------------------------------------------------
// Universal MFMA GEMM.  C[z] = epilogue(A @ Bt[z]^T).
// A: [M][K] fp32 (ABF=0, converted during staging) or bf16 (ABF=1).
// Bt: bf16 [N][K] (B^T layout, ldb=K).  K multiple of 64.
// OUTB=1: C bf16 = f2bf(acc*alpha).  OUTB=0: C fp32 = (acc+bias)*alpha+beta*res.
// ---------------------------------------------------------------------------
struct MgP {
  const void* A;
  const unsigned short* Bt0; const unsigned short* Bt1; const unsigned short* Bt2;
  void* C0; void* C1; void* C2;
  const float* bias; const float* res;
  float a0, a1, a2, beta;
  int lda, ldc, K;
};

template<int BM,int BN,bool ABF,bool OUTB>
__global__ __launch_bounds__(256) void mg_k(MgP p)
{
  __shared__ char smem[(BM+BN)*128];
  unsigned short* As = (unsigned short*)smem;
  unsigned short* Bs = (unsigned short*)(smem + BM*128);
  const int z = blockIdx.z;
  const unsigned short* Bt = (z==0)? p.Bt0 : ((z==1)? p.Bt1 : p.Bt2);
  void* C = (z==0)? p.C0 : ((z==1)? p.C1 : p.C2);
  const float alpha = (z==0)? p.a0 : ((z==1)? p.a1 : p.a2);
  const int bm = blockIdx.y*BM, bn = blockIdx.x*BN;
  const int tid = threadIdx.x, lane = tid&63, wid = tid>>6;
  constexpr int WTM = BM/2, WTN = BN/2, MT = WTM/16, NT = WTN/16;
  const int wr = (wid>>1)*WTM, wc = (wid&1)*WTN;
  const int r = lane&15, g = lane>>4;
  f32x4 acc[MT][NT];
#pragma unroll
  for (int mi=0;mi<MT;mi++)
#pragma unroll
    for (int ni=0;ni<NT;ni++) acc[mi][ni] = (f32x4){0,0,0,0};

  for (int k0=0; k0<p.K; k0+=64){
    __syncthreads();
#pragma unroll
    for (int pp=0; pp<BM*8/256; pp++){
      int e = tid + pp*256; int row=e>>3, cb=e&7;
      s16x8 v;
      if (ABF) {
        v = *(const s16x8*)((const unsigned short*)p.A + (size_t)(bm+row)*p.lda + k0 + cb*8);
      } else {
        const float* ap = (const float*)p.A + (size_t)(bm+row)*p.lda + k0 + cb*8;
        float4 f0 = *(const float4*)ap, f1 = *(const float4*)(ap+4);
        v[0]=(short)f2bf(f0.x); v[1]=(short)f2bf(f0.y); v[2]=(short)f2bf(f0.z); v[3]=(short)f2bf(f0.w);
        v[4]=(short)f2bf(f1.x); v[5]=(short)f2bf(f1.y); v[6]=(short)f2bf(f1.z); v[7]=(short)f2bf(f1.w);
      }
      *(s16x8*)((char*)As + row*128 + ((cb^(row&7))*16)) = v;
    }
#pragma unroll
    for (int pp=0; pp<BN*8/256; pp++){
      int e = tid + pp*256; int row=e>>3, cb=e&7;
      *(s16x8*)((char*)Bs + row*128 + ((cb^(row&7))*16)) =
          *(const s16x8*)(Bt + (size_t)(bn+row)*p.K + k0 + cb*8);
    }
    __syncthreads();
#pragma unroll
    for (int kk=0; kk<2; kk++){
      s16x8 a[MT], b[NT];
#pragma unroll
      for (int mi=0;mi<MT;mi++){
        int row = wr+mi*16+r; int cb = kk*4+g;
        a[mi] = *(const s16x8*)((const char*)As + row*128 + ((cb^(row&7))*16));
      }
#pragma unroll
      for (int ni=0;ni<NT;ni++){
        int row = wc+ni*16+r; int cb = kk*4+g;
        b[ni] = *(const s16x8*)((const char*)Bs + row*128 + ((cb^(row&7))*16));
      }
#pragma unroll
      for (int mi=0;mi<MT;mi++)
#pragma unroll
        for (int ni=0;ni<NT;ni++)
          acc[mi][ni] = MFMA(a[mi], b[ni], acc[mi][ni]);
    }
  }
#pragma unroll
  for (int mi=0;mi<MT;mi++)
#pragma unroll
    for (int ni=0;ni<NT;ni++)
#pragma unroll
      for (int q=0;q<4;q++){
        int row = bm + wr + mi*16 + g*4 + q;
        int col = bn + wc + ni*16 + r;
        float v = acc[mi][ni][q];
        if (OUTB) {
          ((unsigned short*)C)[(size_t)row*p.ldc + col] = f2bf(v*alpha);
        } else {
          if (p.bias) v += p.bias[col];
          v *= alpha;
          if (p.beta != 0.f) v += p.beta * p.res[(size_t)row*p.ldc + col];
          ((float*)C)[(size_t)row*p.ldc + col] = v;
        }
      }
}

// ---------------------------------------------------------------------------
// Convert+transpose fp32 W[K][N] -> bf16 WT[N][K]
// ---------------------------------------------------------------------------
__global__ __launch_bounds__(256) void cvtT_k(const float* __restrict__ W,
                                              unsigned short* __restrict__ WT,
                                              int K, int N)
{
  __shared__ unsigned short t[32][33];
  const int kb = blockIdx.y*32, nb = blockIdx.x*32;
  const int tx = threadIdx.x & 31, ty = threadIdx.x >> 5;
#pragma unroll
  for (int i = ty; i < 32; i += 8)
    t[i][tx] = f2bf(W[(size_t)(kb+i)*N + nb + tx]);
  __syncthreads();
#pragma unroll
  for (int i = ty; i < 32; i += 8)
    WT[(size_t)(nb+i)*K + kb + tx] = t[tx][i];
}

// Batched small-weight transpose-convert: 12 matrices, one launch.
struct CvtD { const float* W; unsigned short* WT; int K, N, off; };
struct CvtMany { CvtD d[12]; };
__global__ __launch_bounds__(256) void cvtT_many_k(CvtMany cm)
{
  int bidx = blockIdx.x;
  int i = 0;
#pragma unroll
  for (int j=1;j<12;j++) if (bidx >= cm.d[j].off) i = j;
  const CvtD dd = cm.d[i];
  int t = bidx - dd.off;
  int ntx = dd.N >> 5;
  const int kb = (t / ntx)*32, nb = (t % ntx)*32;
  __shared__ unsigned short tsh[32][33];
  const int tx = threadIdx.x & 31, ty2 = threadIdx.x >> 5;
#pragma unroll
  for (int j = ty2; j < 32; j += 8)
    tsh[j][tx] = f2bf(dd.W[(size_t)(kb+j)*dd.N + nb + tx]);
  __syncthreads();
#pragma unroll
  for (int j = ty2; j < 32; j += 8)
    dd.WT[(size_t)(nb+j)*dd.K + kb + tx] = tsh[tx][j];
}

// ---------------------------------------------------------------------------
// Flash MFMA attention partials — NO-MAX variant.
// ---------------------------------------------------------------------------
__global__ __launch_bounds__(256, 4) void flash_k(
    const unsigned short* __restrict__ Qb, const unsigned short* __restrict__ Kb,
    const unsigned short* __restrict__ Vb, float* __restrict__ part,
    int S, int nsplit)
{
  __shared__ __align__(16) char smem[25856];
  unsigned short* Ks = (unsigned short*)smem;                 // [64][40]
  unsigned short* VT = (unsigned short*)(smem + 5120);        // [16][72], col ^= ((row&8)<<1)
  const int tid = threadIdx.x, lane = tid & 63, wv = tid >> 6;
  unsigned short* Pw0 = (unsigned short*)(smem + 7424) + wv*2304;
  unsigned short* Pw1 = Pw0 + 1152;

  const int blk = blockIdx.x;
  const int split = blk % nsplit, bh = blk / nsplit;
  const int b = bh >> 3, h = bh & 7;
  const int r = lane & 15, g = lane >> 4;

  {
    int t0 = tid >> 2, c0 = (tid & 3) * 4;
    *(ushort4*)&Ks[t0*40 + 16 + c0] = (ushort4){0,0,0,0};
  }

  s16x8 qa[4];
#pragma unroll
  for (int m=0;m<4;m++){
    if (g < 2)
      qa[m] = *(const s16x8*)(Qb + ((size_t)(b*LS_) + wv*64 + m*16 + r)*INNER_ + h*DH_ + g*8);
    else
      qa[m] = (s16x8){0,0,0,0,0,0,0,0};
  }

  f32x4 oacc[4];
  float den[4][4];
#pragma unroll
  for (int m=0;m<4;m++){
    oacc[m] = (f32x4){0,0,0,0};
#pragma unroll
    for (int q=0;q<4;q++) den[m][q] = 0.f;
  }

  const int len = S / nsplit, s0 = split * len;
  const int xs = (g & 2) << 3;                // P-store column swizzle
  const int gx = g ^ (((r>>3)&1)<<1);         // P-read swizzle
  const int gv = g ^ (((r>>3)&1)<<1);         // V-read swizzle (XOR-16)

  for (int sc = s0; sc < s0 + len; sc += 64) {
    __syncthreads();
    {
      int t0 = tid >> 2, c0 = (tid & 3) * 4;
      size_t base = ((size_t)(b)*S + sc + t0)*INNER_ + h*DH_ + c0;
      ushort4 kv = *(const ushort4*)(Kb + base);
      *(ushort4*)&Ks[t0*40 + c0] = kv;
      ushort4 vv = *(const ushort4*)(Vb + base);
      VT[(c0+0)*72 + (t0 ^ (((c0+0)&8)<<1))] = vv.x;
      VT[(c0+1)*72 + (t0 ^ (((c0+1)&8)<<1))] = vv.y;
      VT[(c0+2)*72 + (t0 ^ (((c0+2)&8)<<1))] = vv.z;
      VT[(c0+3)*72 + (t0 ^ (((c0+3)&8)<<1))] = vv.w;
    }
    __syncthreads();

    s16x8 bk[4];
#pragma unroll
    for (int n=0;n<4;n++) bk[n] = *(const s16x8*)&Ks[(n*16+r)*40 + g*8];
    s16x8 bv0 = *(const s16x8*)&VT[r*72 + gv*8];
    s16x8 bv1 = *(const s16x8*)&VT[r*72 + 32 + gv*8];

#pragma unroll
    for (int m=0;m<4;m++){
      f32x4 sv[4];
#pragma unroll
      for (int n=0;n<4;n++) sv[n] = MFMA(qa[m], bk[n], (f32x4){0,0,0,0});
      unsigned short* Pw = (m & 1) ? Pw1 : Pw0;
#pragma unroll
      for (int q=0;q<4;q++){
        float p0 = exp2f(sv[0][q]);
        float p1 = exp2f(sv[1][q]);
        float p2 = exp2f(sv[2][q]);
        float p3 = exp2f(sv[3][q]);
        den[m][q] += (p0+p1)+(p2+p3);
        unsigned short* pr = &Pw[(g*4+q)*72];
        pr[( 0^xs)+r] = f2bf(p0);
        pr[(16^xs)+r] = f2bf(p1);
        pr[(32^xs)+r] = f2bf(p2);
        pr[(48^xs)+r] = f2bf(p3);
      }
      s16x8 pa0 = *(const s16x8*)&Pw[r*72 + gx*8];
      s16x8 pa1 = *(const s16x8*)&Pw[r*72 + 32 + gx*8];
      oacc[m] = MFMA(pa0, bv0, oacc[m]);
      oacc[m] = MFMA(pa1, bv1, oacc[m]);
    }
  }

#pragma unroll
  for (int m=0;m<4;m++)
#pragma unroll
    for (int q=0;q<4;q++){
      float d = den[m][q];
#pragma unroll
      for (int off=1; off<16; off<<=1) d += __shfl_xor(d, off);
      den[m][q] = d;
    }

  float* pp = part + (size_t)(bh*nsplit + split)*(LS_*18);
#pragma unroll
  for (int m=0;m<4;m++)
#pragma unroll
    for (int q=0;q<4;q++){
      int row = wv*64 + m*16 + g*4 + q;
      if (r == 0) pp[LS_ + row] = den[m][q];
      pp[(2+r)*LS_ + row] = oacc[m][q];
    }
}

__global__ __launch_bounds__(256) void attn_combine_k(
    const float* __restrict__ part, unsigned short* __restrict__ O, int nsplit)
{
  const int idx = blockIdx.x*256 + threadIdx.x;
  const int bh = idx >> 8;
  const int l  = idx & 255;
  const int b = bh >> 3, h = bh & 7;
  float sum = 0.f;
  float acc[16];
#pragma unroll
  for (int d=0; d<16; d++) acc[d]=0.f;
  for (int sp=0; sp<nsplit; sp++) {
    const float* pp = part + (size_t)(bh*nsplit+sp)*(LS_*18);
    sum += pp[LS_+l];
#pragma unroll
    for (int d=0; d<16; d++) acc[d] += pp[(2+d)*LS_+l];
  }
  float inv = 1.0f / sum;
  unsigned short* op = O + ((size_t)(b*LS_ + l)*INNER_ + h*DH_);
#pragma unroll
  for (int d=0; d<16; d++) op[d] = f2bf(acc[d]*inv);
}

// ---------------------------------------------------------------------------
// MFMA FFW hidden (64x64 tile, K=128), single CH=16384 chunk
// ---------------------------------------------------------------------------
__global__ __launch_bounds__(256) void ffw_hidden_mfma_k(
    const unsigned short* __restrict__ Ab, const unsigned short* __restrict__ W1T,
    const float* __restrict__ b1, unsigned short* __restrict__ Hb)
{
  __shared__ char smem[48*1024];
  unsigned short* As  = (unsigned short*)smem;
  unsigned short* B1s = (unsigned short*)(smem+16384);
  unsigned short* B2s = (unsigned short*)(smem+32768);
  const int bm = blockIdx.y*64, bn = blockIdx.x*64;
  const int tid = threadIdx.x;
#pragma unroll
  for (int p=0;p<4;p++){
    int e = tid + p*256; int row = e>>4, cb = e&15;
    int sw = (cb ^ (row&7))*16;
    *(s16x8*)((char*)As  + row*256 + sw) = *(const s16x8*)(Ab  + (size_t)(bm+row)*LC_ + cb*8);
    *(s16x8*)((char*)B1s + row*256 + sw) = *(const s16x8*)(W1T + (size_t)(bn+row)*LC_ + cb*8);
    *(s16x8*)((char*)B2s + row*256 + sw) = *(const s16x8*)(W1T + ((size_t)FFH_+bn+row)*LC_ + cb*8);
  }
  __syncthreads();
  const int lane = tid&63, wid = tid>>6;
  const int wr = (wid>>1)*32, wc = (wid&1)*32;
  const int r = lane&15, g = lane>>4;
  f32x4 acc1[2][2], acc2[2][2];
#pragma unroll
  for (int mi=0;mi<2;mi++)
#pragma unroll
    for (int ni=0;ni<2;ni++){ acc1[mi][ni]=(f32x4){0,0,0,0}; acc2[mi][ni]=(f32x4){0,0,0,0}; }
#pragma unroll
  for (int ks=0; ks<4; ks++){
    const int cb = ks*4 + g;
    s16x8 a[2], bf1[2], bf2[2];
#pragma unroll
    for (int mi=0;mi<2;mi++){
      int row = wr+mi*16+r; int sw=(cb^(row&7))*16;
      a[mi] = *(const s16x8*)((const char*)As + row*256 + sw);
    }
#pragma unroll
    for (int ni=0;ni<2;ni++){
      int row = wc+ni*16+r; int sw=(cb^(row&7))*16;
      bf1[ni] = *(const s16x8*)((const char*)B1s + row*256 + sw);
      bf2[ni] = *(const s16x8*)((const char*)B2s + row*256 + sw);
    }
#pragma unroll
    for (int mi=0;mi<2;mi++)
#pragma unroll
      for (int ni=0;ni<2;ni++){
        acc1[mi][ni] = MFMA(a[mi], bf1[ni], acc1[mi][ni]);
        acc2[mi][ni] = MFMA(a[mi], bf2[ni], acc2[mi][ni]);
      }
  }
  __syncthreads();
  unsigned short* Ts = (unsigned short*)smem;   // [64][72]
#pragma unroll
  for (int mi=0;mi<2;mi++)
#pragma unroll
    for (int ni=0;ni<2;ni++)
#pragma unroll
      for (int q=0;q<4;q++){
        int row = wr + mi*16 + g*4 + q;
        int col = wc + ni*16 + r;
        int colg = bn + col;
        float u1 = acc1[mi][ni][q] + b1[colg];
        float u2 = acc2[mi][ni][q] + b1[FFH_ + colg];
        float ge = 0.5f*u2*(1.0f + erff(u2*0.70710678118654752440f));
        Ts[row*72 + col] = f2bf(u1*ge);
      }
  __syncthreads();
#pragma unroll
  for (int p=0;p<2;p++){
    int e = tid + p*256; int row = e>>3, cb = e&7;
    *(s16x8*)(Hb + (size_t)(bm+row)*CH_ + bn + cb*8) =
        *(const s16x8*)((const char*)Ts + row*144 + cb*16);
  }
}

// ---------------------------------------------------------------------------
// MFMA FFW second GEMM, split-K(256), atomic accumulate into fp32 lat.
// ---------------------------------------------------------------------------
__global__ __launch_bounds__(256) void ffw2_mfma_k(
    const unsigned short* __restrict__ Hb, const unsigned short* __restrict__ W2T,
    float* __restrict__ C)
{
  __shared__ char smem[24*1024];
  unsigned short* As = (unsigned short*)smem;
  unsigned short* Bs = (unsigned short*)(smem+8192);
  const int bm = blockIdx.y*64;
  const int k0 = blockIdx.x*256;
  const int tid = threadIdx.x;
  const int lane = tid&63, wid = tid>>6;
  const int wr = (wid>>1)*32, wc = (wid&1)*64;
  const int r = lane&15, g = lane>>4;
  f32x4 acc[2][4];
#pragma unroll
  for (int mi=0;mi<2;mi++)
#pragma unroll
    for (int ni=0;ni<4;ni++) acc[mi][ni]=(f32x4){0,0,0,0};

  for (int kb=0; kb<256; kb+=64){
    __syncthreads();
#pragma unroll
    for (int p=0;p<2;p++){
      int e = tid + p*256; int row=e>>3, cb=e&7;
      int sw = (cb ^ (row&7))*16;
      *(s16x8*)((char*)As + row*128 + sw) =
          *(const s16x8*)(Hb + (size_t)(bm+row)*CH_ + k0+kb+cb*8);
    }
#pragma unroll
    for (int p=0;p<4;p++){
      int e = tid + p*256; int row=e>>3, cb=e&7;
      int sw = (cb ^ (row&7))*16;
      *(s16x8*)((char*)Bs + row*128 + sw) =
          *(const s16x8*)(W2T + (size_t)row*FFH_ + k0+kb+cb*8);
    }
    __syncthreads();
#pragma unroll
    for (int ks=0; ks<2; ks++){
      const int cb = ks*4 + g;
      s16x8 a[2], b[4];
#pragma unroll
      for (int mi=0;mi<2;mi++){
        int row = wr+mi*16+r; int sw=(cb^(row&7))*16;
        a[mi] = *(const s16x8*)((const char*)As + row*128 + sw);
      }
#pragma unroll
      for (int ni=0;ni<4;ni++){
        int row = wc+ni*16+r; int sw=(cb^(row&7))*16;
        b[ni] = *(const s16x8*)((const char*)Bs + row*128 + sw);
      }
#pragma unroll
      for (int mi=0;mi<2;mi++)
#pragma unroll
        for (int ni=0;ni<4;ni++)
          acc[mi][ni] = MFMA(a[mi], b[ni], acc[mi][ni]);
    }
  }
#pragma unroll
  for (int mi=0;mi<2;mi++)
#pragma unroll
    for (int ni=0;ni<4;ni++)
#pragma unroll
      for (int q=0;q<4;q++){
        int row = bm + wr + mi*16 + g*4 + q;
        int col = wc + ni*16 + r;
        atomicAdd(&C[(size_t)row*LC_ + col], acc[mi][ni][q]);
      }
}

// ---------------------------------------------------------------------------
// Small kernels
// ---------------------------------------------------------------------------
__global__ __launch_bounds__(256) void bcast_k(const float* __restrict__ src,
                                               float* __restrict__ dst)
{
  int i = blockIdx.x*256 + threadIdx.x;
  dst[i] = src[i & (LS_*LC_ - 1)];
}

__global__ __launch_bounds__(256) void ln_b2_k(float* __restrict__ x,
                                               const float* __restrict__ g,
                                               const float* __restrict__ bta,
                                               const float* __restrict__ b2,
                                               unsigned short* __restrict__ yb, int rows)
{
  int w = (blockIdx.x * blockDim.x + threadIdx.x) >> 6;
  int lane = threadIdx.x & 63;
  if (w >= rows) return;
  float* xr = x + (size_t)w*LC_;
  float x0 = xr[lane], x1 = xr[lane+64];
  float s = x0 + x1;
#pragma unroll
  for (int off=32; off; off>>=1) s += __shfl_xor(s, off);
  float mu = s * (1.0f/128.0f);
  float d0 = x0-mu, d1 = x1-mu;
  float v = d0*d0 + d1*d1;
#pragma unroll
  for (int off=32; off; off>>=1) v += __shfl_xor(v, off);
  float rstd = rsqrtf(v*(1.0f/128.0f) + 1e-5f);
  unsigned short* yr = yb + (size_t)w*LC_;
  yr[lane]    = f2bf(d0*rstd*g[lane]    + bta[lane]);
  yr[lane+64] = f2bf(d1*rstd*g[lane+64] + bta[lane+64]);
  xr[lane]    = x0 + b2[lane];
  xr[lane+64] = x1 + b2[lane+64];
}

// ---------------------------------------------------------------------------
extern "C" void kernel_launch(void* const* d_in, const int* in_sizes, int n_in,
                              void* d_out, int out_size, void* d_ws, size_t ws_size,
                              hipStream_t stream)
{
  (void)in_sizes; (void)n_in; (void)out_size; (void)ws_size;
  const float* data    = (const float*)d_in[0];
  const float* inilat  = (const float*)d_in[1];
  const float* ca_Wq   = (const float*)d_in[2];
  const float* ca_Wk   = (const float*)d_in[3];
  const float* ca_Wv   = (const float*)d_in[4];
  const float* ca_Wo   = (const float*)d_in[5];
  const float* ca_bo   = (const float*)d_in[6];
  const float* tr_Wq   = (const float*)d_in[7];
  const float* tr_Wk   = (const float*)d_in[8];
  const float* tr_Wv   = (const float*)d_in[9];
  const float* tr_Wo   = (const float*)d_in[10];
  const float* tr_bo   = (const float*)d_in[11];
  const float* caff_g  = (const float*)d_in[12];
  const float* caff_b  = (const float*)d_in[13];
  const float* caff_W1 = (const float*)d_in[14];
  const float* caff_b1 = (const float*)d_in[15];
  const float* caff_W2 = (const float*)d_in[16];
  const float* caff_b2 = (const float*)d_in[17];
  const float* trff_g  = (const float*)d_in[18];
  const float* trff_b  = (const float*)d_in[19];
  const float* trff_W1 = (const float*)d_in[20];
  const float* trff_b1 = (const float*)d_in[21];
  const float* trff_W2 = (const float*)d_in[22];
  const float* trff_b2 = (const float*)d_in[23];

  float* lat = (float*)d_ws;
  float* zb  = lat + LATSZ_;
  unsigned short* Obf  = (unsigned short*)(zb + LATSZ_);
  unsigned short* Qbf  = Obf + LATSZ_;
  unsigned short* Klbf = Qbf + LATSZ_;
  unsigned short* Vlbf = Klbf + LATSZ_;
  unsigned short* xnb  = Vlbf + LATSZ_;
  unsigned short* Kdbf = xnb + LATSZ_;
  unsigned short* Vdbf = Kdbf + (size_t)B_*DS_*INNER_;
  unsigned short* W1Tc = Vdbf + (size_t)B_*DS_*INNER_;
  unsigned short* W1Tt = W1Tc + (size_t)2*FFH_*LC_;
  unsigned short* W2Tc = W1Tt + (size_t)2*FFH_*LC_;
  unsigned short* W2Tt = W2Tc + (size_t)FFH_*LC_;
  unsigned short* caWqT = W2Tt + (size_t)FFH_*LC_;     // [128][128]
  unsigned short* caWkT = caWqT + LC_*INNER_;          // [128][64]
  unsigned short* caWvT = caWkT + INNER_*DC_;
  unsigned short* caWoT = caWvT + INNER_*DC_;          // [128][128]
  unsigned short* trT   = caWoT + INNER_*LC_;          // 8 x [128][128]
  unsigned short* scratch = trT + (size_t)8*LC_*INNER_;
  float* part = (float*)scratch;                       // attn phases
  unsigned short* hb = (unsigned short*)scratch;       // ffw phases (aliased)

  // --- weight conversions ---
  hipLaunchKernelGGL(cvtT_k, dim3(2*FFH_/32, LC_/32), dim3(256), 0, stream, caff_W1, W1Tc, LC_, 2*FFH_);
  hipLaunchKernelGGL(cvtT_k, dim3(2*FFH_/32, LC_/32), dim3(256), 0, stream, trff_W1, W1Tt, LC_, 2*FFH_);
  hipLaunchKernelGGL(cvtT_k, dim3(LC_/32, FFH_/32), dim3(256), 0, stream, caff_W2, W2Tc, FFH_, LC_);
  hipLaunchKernelGGL(cvtT_k, dim3(LC_/32, FFH_/32), dim3(256), 0, stream, trff_W2, W2Tt, FFH_, LC_);

  CvtMany cm; int off = 0;
  auto addD = [&](int i, const float* W, unsigned short* WT, int K, int N){
    cm.d[i].W = W; cm.d[i].WT = WT; cm.d[i].K = K; cm.d[i].N = N; cm.d[i].off = off;
    off += (K/32)*(N/32);
  };
  addD(0, ca_Wq, caWqT, LC_, INNER_);
  addD(1, ca_Wk, caWkT, DC_, INNER_);
  addD(2, ca_Wv, caWvT, DC_, INNER_);
  addD(3, ca_Wo, caWoT, INNER_, LC_);
  for (int t=0;t<2;t++) addD(4+t,  tr_Wq + (size_t)t*LC_*INNER_, trT + (size_t)(0*2+t)*LC_*INNER_, LC_, INNER_);
  for (int t=0;t<2;t++) addD(6+t,  tr_Wk + (size_t)t*LC_*INNER_, trT + (size_t)(1*2+t)*LC_*INNER_, LC_, INNER_);
  for (int t=0;t<2;t++) addD(8+t,  tr_Wv + (size_t)t*LC_*INNER_, trT + (size_t)(2*2+t)*LC_*INNER_, LC_, INNER_);
  for (int t=0;t<2;t++) addD(10+t, tr_Wo + (size_t)t*INNER_*LC_, trT + (size_t)(3*2+t)*LC_*INNER_, INNER_, LC_);
  hipLaunchKernelGGL(cvtT_many_k, dim3(off), dim3(256), 0, stream, cm);

  hipLaunchKernelGGL(bcast_k, dim3(LATSZ_/256), dim3(256), 0, stream, inilat, lat);

  // K/V data projections: bf16 MFMA
  {
    MgP p = {};
    p.A = data; p.lda = DC_; p.K = DC_; p.ldc = INNER_;
    p.Bt0 = caWkT; p.Bt1 = caWvT; p.C0 = Kdbf; p.C1 = Vdbf;
    p.a0 = 1.f; p.a1 = 1.f;
    hipLaunchKernelGGL((mg_k<128,128,false,true>), dim3(1, B_*DS_/128, 2), dim3(256), 0, stream, p);
  }

  auto cross_attend = [&](float alpha, float beta) {
    MgP q = {};
    q.A = lat; q.lda = LC_; q.K = LC_; q.ldc = INNER_;
    q.Bt0 = caWqT; q.C0 = Qbf; q.a0 = QS_;
    hipLaunchKernelGGL((mg_k<64,64,false,true>), dim3(2, 16, 1), dim3(256), 0, stream, q);
    hipLaunchKernelGGL(flash_k, dim3(B_*H_*NSPL_CROSS), dim3(256), 0, stream,
                       Qbf, Kdbf, Vdbf, part, DS_, NSPL_CROSS);
    hipLaunchKernelGGL(attn_combine_k, dim3(B_*H_*LS_/256), dim3(256), 0, stream, part, Obf, NSPL_CROSS);
    MgP w = {};
    w.A = Obf; w.lda = INNER_; w.K = INNER_; w.ldc = LC_;
    w.Bt0 = caWoT; w.C0 = lat; w.bias = ca_bo; w.res = lat;
    w.a0 = alpha; w.beta = beta;
    hipLaunchKernelGGL((mg_k<64,64,true,false>), dim3(2, 16, 1), dim3(256), 0, stream, w);
  };

  auto self_layer = [&](const float* in, float* out, int t, float alpha, float beta, const float* res) {
    MgP q = {};
    q.A = in; q.lda = LC_; q.K = LC_; q.ldc = INNER_;
    q.Bt0 = trT + (size_t)(0*2+t)*LC_*INNER_;
    q.Bt1 = trT + (size_t)(1*2+t)*LC_*INNER_;
    q.Bt2 = trT + (size_t)(2*2+t)*LC_*INNER_;
    q.C0 = Qbf; q.C1 = Klbf; q.C2 = Vlbf;
    q.a0 = QS_; q.a1 = 1.f; q.a2 = 1.f;
    hipLaunchKernelGGL((mg_k<64,64,false,true>), dim3(2, 16, 3), dim3(256), 0, stream, q);
    hipLaunchKernelGGL(flash_k, dim3(B_*H_*NSPL_SELF), dim3(256), 0, stream,
                       Qbf, Klbf, Vlbf, part, LS_, NSPL_SELF);
    hipLaunchKernelGGL(attn_combine_k, dim3(B_*H_*LS_/256), dim3(256), 0, stream, part, Obf, NSPL_SELF);
    MgP w = {};
    w.A = Obf; w.lda = INNER_; w.K = INNER_; w.ldc = LC_;
    w.Bt0 = trT + (size_t)(3*2+t)*LC_*INNER_;
    w.C0 = out; w.bias = tr_bo + (size_t)t*LC_; w.res = res;
    w.a0 = alpha; w.beta = beta;
    hipLaunchKernelGGL((mg_k<64,64,true,false>), dim3(2, 16, 1), dim3(256), 0, stream, w);
  };

  auto ffw = [&](const float* g, const float* bta,
                 const unsigned short* W1T, const float* b1,
                 const unsigned short* W2T, const float* b2) {
    hipLaunchKernelGGL(ln_b2_k, dim3(NLAT_/4), dim3(256), 0, stream, lat, g, bta, b2, xnb, NLAT_);
    hipLaunchKernelGGL(ffw_hidden_mfma_k, dim3(CH_/64, NLAT_/64), dim3(256), 0, stream,
                       xnb, W1T, b1, hb);
    hipLaunchKernelGGL(ffw2_mfma_k, dim3(CH_/256, NLAT_/64), dim3(256), 0, stream,
                       hb, W2T, lat);
  };

  cross_attend(1.f, 0.f);
  self_layer(lat, zb, 0, 1.f, 0.f, nullptr);
  self_layer(zb, lat, 1, 1.f, 0.f, nullptr);

  for (int na = 0; na < 2; na++) {
    cross_attend(0.5f, 0.5f);
    ffw(caff_g, caff_b, W1Tc, caff_b1, W2Tc, caff_b2);
    self_layer(lat, zb, 0, 1.f, 0.f, nullptr);
    self_layer(zb, lat, 1, 0.5f, 0.5f, lat);
    ffw(trff_g, trff_b, W1Tt, trff_b1, W2Tt, trff_b2);
  }

  hipMemcpyAsync(d_out, lat, (size_t)LATSZ_*sizeof(float), hipMemcpyDeviceToDevice, stream);
}